// Round 8
// baseline (2853.287 us; speedup 1.0000x reference)
//
#include <hip/hip_runtime.h>
#include <hip/hip_bf16.h>

#define BATCH 32
#define MAXPV 50
#define RN 256
#define PN 256
#define DIM 128
#define NPV (BATCH*MAXPV*DIM)

typedef unsigned short u16;

// ---- all intermediates in the code object ----
__device__ float g_p[NPV], g_v[NPV], g_pa[NPV], g_pb[NPV], g_pc[NPV];
__device__ float g_ra[RN*DIM], g_rb[RN*DIM], g_rc[RN*DIM], g_pp1[PN*DIM];
__device__ float g_prop[PN*DIM], g_re[RN*DIM];
__device__ float g_rmask[RN], g_regp[RN], g_score[BATCH*RN];
__device__ int   g_ftype;   // 0=fp32, 1=bf16
__device__ int   g_i64;     // 0=int32, 1=int64

__device__ __forceinline__ float bf2f(u16 u){ return __uint_as_float(((unsigned)u)<<16); }
__device__ __forceinline__ float LD(const void* p, size_t i){
    return g_ftype ? bf2f(((const u16*)p)[i]) : ((const float*)p)[i];
}
__device__ __forceinline__ int LDI(const void* p, size_t i){
    return g_i64 ? (int)((const long long*)p)[i] : ((const int*)p)[i];
}

__device__ __forceinline__ float wred(float v){
#pragma unroll
    for(int o=32;o;o>>=1) v += __shfl_xor(v,o,64);
    return v;
}
__device__ __forceinline__ double wredd(double v){
#pragma unroll
    for(int o=32;o;o>>=1) v += __shfl_xor(v,o,64);
    return v;
}
__device__ __forceinline__ float wmax(float v){
#pragma unroll
    for(int o=32;o;o>>=1) v = fmaxf(v,__shfl_xor(v,o,64));
    return v;
}
__device__ __forceinline__ float sigm(float x){ return 1.f/(1.f+expf(-x)); }
__device__ __forceinline__ double sigmd(double x){ return 1.0/(1.0+exp(-x)); }

// ---------------- Kernel 0: classify float dtype + int width ----------------
__global__ void k_detect(const u16* __restrict__ ent, const unsigned* __restrict__ prop){
    __shared__ int c[2];
    int t = threadIdx.x;                 // 256 threads
    if(t<2) c[t] = 0;
    __syncthreads();
    int ee = (ent[2*(size_t)t*977]>>7)&0xFF;   // max idx 498,270 < 6.4M (safe both dtypes)
    if(ee>=120 && ee<=133) atomicAdd(&c[0],1);
    if(t<32 && prop[2*t+1]==0u) atomicAdd(&c[1],1);
    __syncthreads();
    if(t==0){
        g_ftype = (c[0]>=200) ? 1 : 0;
        g_i64   = (c[1]>=30) ? 1 : 0;
    }
}

// ---------------- Kernel 1: gather + l2-normalize rows ----------------
__global__ void k_norm(const void* __restrict__ ent, const void* __restrict__ rule,
                       const void* __restrict__ prop, const void* __restrict__ val){
    int row = blockIdx.x*4 + (threadIdx.x>>6);
    int l = threadIdx.x & 63;
    const void* src; size_t off; float* dst;
    if(row < 1600){ src = ent; off = (size_t)LDI(prop,row)*DIM; dst = g_p + (size_t)row*DIM; }
    else if(row < 3200){ int i=row-1600; src = ent; off = (size_t)LDI(val,i)*DIM; dst = g_v + (size_t)i*DIM; }
    else if(row < 3456){ int i=row-3200; src = rule; off = (size_t)i*DIM; dst = g_re + (size_t)i*DIM; }
    else { int i=row-3456; src = ent; off = (size_t)i*DIM; dst = g_prop + (size_t)i*DIM; }
    float a = LD(src, off+l), b = LD(src, off+l+64);
    float n = fmaxf(sqrtf((float)wredd((double)a*a+(double)b*b)), 1e-12f);
    dst[l] = a/n; dst[l+64] = b/n;
}

// ---------------- Kernel 2: row matmuls ----------------
__global__ void k_mm(const void* __restrict__ fc1w, const void* __restrict__ fc2w, const void* __restrict__ fc3w,
                     const void* __restrict__ fc1b, const void* __restrict__ fc2b, const void* __restrict__ fc3b){
    __shared__ float row[DIM];
    int blk = blockIdx.x, j = threadIdx.x;
    const float* in; const void* w; size_t woff = 0; float bias = 0.f; float* out;
    if(blk < 1600){ in=g_p+(size_t)blk*DIM; w=fc1w; out=g_pa+(size_t)blk*DIM; }
    else if(blk < 3200){ int i=blk-1600; in=g_p+(size_t)i*DIM; w=fc2w; out=g_pb+(size_t)i*DIM; }
    else if(blk < 4800){ int i=blk-3200; in=g_p+(size_t)i*DIM; w=fc3w; out=g_pc+(size_t)i*DIM; }
    else if(blk < 5056){ int i=blk-4800; in=g_re+(size_t)i*DIM; w=fc1w; woff=DIM*DIM; out=g_ra+(size_t)i*DIM; bias=LD(fc1b,j); }
    else if(blk < 5312){ int i=blk-5056; in=g_re+(size_t)i*DIM; w=fc2w; woff=DIM*DIM; out=g_rb+(size_t)i*DIM; bias=LD(fc2b,j); }
    else if(blk < 5568){ int i=blk-5312; in=g_re+(size_t)i*DIM; w=fc3w; woff=DIM*DIM; out=g_rc+(size_t)i*DIM; bias=LD(fc3b,j); }
    else { int i=blk-5568; in=g_prop+(size_t)i*DIM; w=fc1w; out=g_pp1+(size_t)i*DIM; }
    row[j] = in[j];
    __syncthreads();
    double acc = (double)bias;
    for(int k=0;k<DIM;k++) acc += (double)row[k]*(double)LD(w, woff + (size_t)k*DIM + j);
    out[j] = (float)acc;
}

// ---------------- Kernel 3: pi -> rule_mask + reg partials (fp64 gates) ----------------
__global__ void k_pi(const void* __restrict__ fc4w, const void* __restrict__ fc4b){
    int r = blockIdx.x, w = threadIdx.x>>6, l = threadIdx.x&63;
    double b4 = (double)LD(fc4b,0);
    float ral = g_ra[r*DIM+l], rah = g_ra[r*DIM+l+64];
    double f4l = (double)LD(fc4w,l), f4h = (double)LD(fc4w,l+64);
    double mask_acc = 0.0, reg_acc = 0.0;
    for(int p = w; p < PN; p += 4){
        double a = (double)fmaxf(g_pp1[p*DIM+l]+ral,0.f)*f4l
                 + (double)fmaxf(g_pp1[p*DIM+l+64]+rah,0.f)*f4h;
        double piv = sigmd(wredd(a) + b4);
        if(l==0){
            if(piv > 0.5) mask_acc += piv;
            double eff = (p==r)? piv : (1.0-piv);
            double wgt = (p==r)? (double)RN : 1.0;
            reg_acc += -log(eff+1e-8)*wgt;
        }
    }
    __shared__ double sm[4], sr[4];
    if(l==0){ sm[w]=mask_acc; sr[w]=reg_acc; }
    __syncthreads();
    if(threadIdx.x==0){
        g_rmask[r] = (float)(1.0 + sm[0]+sm[1]+sm[2]+sm[3]);
        g_regp[r]  = (float)(sr[0]+sr[1]+sr[2]+sr[3]);
    }
}

// ---------------- Kernel 4: main fused scoring, one block per (b,r) ----------------
__global__ __launch_bounds__(256) void k_main(
    const void* __restrict__ fc6w, const void* __restrict__ fc6b,
    const void* __restrict__ fc4w, const void* __restrict__ fc4b,
    const void* __restrict__ fc5w, const void* __restrict__ fc5b,
    const void* __restrict__ same, const void* __restrict__ pad){
    __shared__ float f6[DIM*DIM];      // 64 KiB fc6 in fp32
    for(int t=threadIdx.x; t<DIM*DIM; t+=256) f6[t] = LD(fc6w,t);
    __syncthreads();
    const int r = blockIdx.x & 255, b = blockIdx.x >> 8;
    const int w = threadIdx.x >> 6, l = threadIdx.x & 63;
    const float ral = g_ra[r*DIM+l], rah = g_ra[r*DIM+l+64];
    const float rbl = g_rb[r*DIM+l], rbh = g_rb[r*DIM+l+64];
    const float rcl = g_rc[r*DIM+l], rch = g_rc[r*DIM+l+64];
    const double f4l = (double)LD(fc4w,l), f4h = (double)LD(fc4w,l+64);
    const float f5l = LD(fc5w,l), f5h = LD(fc5w,l+64);
    const float f6bl = LD(fc6b,l), f6bh = LD(fc6b,l+64);
    const double b4 = (double)LD(fc4b,0);
    const float b5 = LD(fc5b,0);
    float acc = 0.f;
    for(int pv = w; pv < MAXPV; pv += 4){
        const size_t i = (size_t)b*MAXPV + pv;
        const float* pai = g_pa + i*DIM;
        const float* pbi = g_pb + i*DIM;
        const float* pci = g_pc + i*DIM;
        const float* vei = g_v  + i*DIM;
        // s1 gate in fp64 (decision s1>0.5 must match np)
        double h1l = (double)fmaxf(pai[l]+ral,0.f), h1h = (double)fmaxf(pai[l+64]+rah,0.f);
        double s1  = sigmd(wredd(h1l*f4l + h1h*f4h) + b4);
        float h2l = fmaxf(pbi[l]+rbl,0.f), h2h = fmaxf(pbi[l+64]+rbh,0.f);
        float p   = sigm(wred(h2l*f5l + h2h*f5h) + b5);
        float h3l = fmaxf(pci[l]+rcl,0.f), h3h = fmaxf(pci[l+64]+rch,0.f);
        float xl = f6bl, xh = f6bh;
        for(int k=0;k<64;k++){
            float hk = __shfl(h3l, k, 64);
            xl += hk*f6[k*DIM + l];
            xh += hk*f6[k*DIM + l + 64];
        }
        for(int k=0;k<64;k++){
            float hk = __shfl(h3h, k, 64);
            xl += hk*f6[(k+64)*DIM + l];
            xh += hk*f6[(k+64)*DIM + l + 64];
        }
        float vl = vei[l], vh = vei[l+64];
        float nvb = sqrtf(wred(vl*vl + vh*vh));
        float nx  = sqrtf(wred(xl*xl + xh*xh));
        float dvx = wred(vl*xl + vh*xh);
        float clipnx = fmaxf(nx, 1e-12f);
        float gvn   = nx / clipnx;
        float denom = fmaxf(nvb*gvn, 1e-8f);
        float cosv  = (dvx / clipnx) / denom;
        float s2 = 0.5f*cosv + 0.5f;
        float sc = p + (1.f-p)*s2;
        sc = (LDI(same,i)==1) ? (float)s1*sc : (1.f - (float)s1);
        sc *= (float)LDI(pad,i);
        sc *= (s1 > 0.5) ? 1.f : 0.f;
        acc += sc;
    }
    __syncthreads();               // done reading f6; reuse for reduction
    if(l==0) f6[w] = acc;
    __syncthreads();
    if(threadIdx.x==0)
        g_score[b*RN + r] = (f6[0]+f6[1]+f6[2]+f6[3]) / g_rmask[r];
}

// ---------------- Kernel 5: pooled max + reg mean -> FLOAT32 out ----------------
__global__ void k_fin(float* __restrict__ out){
    int w = threadIdx.x>>6, l = threadIdx.x&63;
#pragma unroll
    for(int i=0;i<8;i++){
        int b = w*8+i;
        float m = -1e30f;
        for(int rr=l; rr<RN; rr+=64) m = fmaxf(m, g_score[b*RN+rr]);
        m = wmax(m);
        if(l==0) out[b] = m;
    }
    __shared__ float s[4];
    float v = g_regp[threadIdx.x & 255];
    v = wred(v);
    if(l==0) s[w]=v;
    __syncthreads();
    if(threadIdx.x==0) out[32] = (s[0]+s[1]+s[2]+s[3]) / (float)(RN*PN);
}

extern "C" void kernel_launch(void* const* d_in, const int* in_sizes, int n_in,
                              void* d_out, int out_size, void* d_ws, size_t ws_size,
                              hipStream_t stream){
    // host-side input-order resolution via in_sizes (inactive under dict order)
    int map[18]; for(int i=0;i<18;i++) map[i]=i;
    if(n_in>=18 && in_sizes[0]==6400000){
        const int a[18] = {14,17,16,13,15,0,2,1,4,3,6,5,8,7,10,9,12,11};
        for(int i=0;i<18;i++) map[i]=a[i];
    }
    const void* prop = d_in[map[0]];
    const void* val  = d_in[map[1]];
    const void* same = d_in[map[2]];
    const void* pad  = d_in[map[3]];
    const void* rule = d_in[map[4]];
    const void* ent  = d_in[map[5]];
    const void* fc1w = d_in[map[6]];
    const void* fc1b = d_in[map[7]];
    const void* fc2w = d_in[map[8]];
    const void* fc2b = d_in[map[9]];
    const void* fc3w = d_in[map[10]];
    const void* fc3b = d_in[map[11]];
    const void* fc4w = d_in[map[12]];
    const void* fc4b = d_in[map[13]];
    const void* fc5w = d_in[map[14]];
    const void* fc5b = d_in[map[15]];
    const void* fc6w = d_in[map[16]];
    const void* fc6b = d_in[map[17]];

    k_detect<<<1, 256, 0, stream>>>((const u16*)ent, (const unsigned*)prop);
    k_norm<<<928, 256, 0, stream>>>(ent, rule, prop, val);
    k_mm<<<5824, 128, 0, stream>>>(fc1w, fc2w, fc3w, fc1b, fc2b, fc3b);
    k_pi<<<RN, 256, 0, stream>>>(fc4w, fc4b);
    k_main<<<BATCH*RN, 256, 0, stream>>>(fc6w, fc6b, fc4w, fc4b, fc5w, fc5b, same, pad);
    k_fin<<<1, 256, 0, stream>>>((float*)d_out);
}

// Round 9
// 380.686 us; speedup vs baseline: 7.4951x; 7.4951x over previous
//
#include <hip/hip_runtime.h>
#include <hip/hip_bf16.h>

#define BATCH 32
#define MAXPV 50
#define RN 256
#define PN 256
#define DIM 128
#define NPV (BATCH*MAXPV*DIM)

typedef unsigned short u16;
typedef __attribute__((ext_vector_type(8))) short short8;
typedef __attribute__((ext_vector_type(4))) float f32x4;

// ---- all intermediates in the code object ----
__device__ float g_p[NPV], g_v[NPV], g_pa[NPV], g_pb[NPV], g_pc[NPV];
__device__ float g_ra[RN*DIM], g_rb[RN*DIM], g_rc[RN*DIM], g_pp1[PN*DIM];
__device__ float g_prop[PN*DIM], g_re[RN*DIM];
__device__ float g_rmask[RN], g_regp[RN], g_ssum[BATCH*RN];
__device__ short8 g_bfrag[8][4][64];   // fc6 B-fragments [ntile][kstep][lane]
__device__ int   g_ftype;   // 0=fp32, 1=bf16
__device__ int   g_i64;     // 0=int32, 1=int64

__device__ __forceinline__ float bf2f(u16 u){ return __uint_as_float(((unsigned)u)<<16); }
__device__ __forceinline__ float LD(const void* p, size_t i){
    return g_ftype ? bf2f(((const u16*)p)[i]) : ((const float*)p)[i];
}
__device__ __forceinline__ int LDI(const void* p, size_t i){
    return g_i64 ? (int)((const long long*)p)[i] : ((const int*)p)[i];
}
__device__ __forceinline__ short f2bf(float f){   // RNE truncate fp32->bf16 bits
    unsigned u = __float_as_uint(f);
    u = (u + 0x7FFFu + ((u>>16)&1u)) >> 16;
    return (short)u;
}

__device__ __forceinline__ float wred(float v){
#pragma unroll
    for(int o=32;o;o>>=1) v += __shfl_xor(v,o,64);
    return v;
}
__device__ __forceinline__ double wredd(double v){
#pragma unroll
    for(int o=32;o;o>>=1) v += __shfl_xor(v,o,64);
    return v;
}
__device__ __forceinline__ float wmax(float v){
#pragma unroll
    for(int o=32;o;o>>=1) v = fmaxf(v,__shfl_xor(v,o,64));
    return v;
}
__device__ __forceinline__ float sigm(float x){ return 1.f/(1.f+expf(-x)); }
__device__ __forceinline__ double sigmd(double x){ return 1.0/(1.0+exp(-x)); }

// ---------------- Kernel 0: classify dtypes + zero score accumulator ----------------
__global__ void k_detect(const u16* __restrict__ ent, const unsigned* __restrict__ prop){
    __shared__ int c[2];
    int t = threadIdx.x;                 // 256 threads
    if(t<2) c[t] = 0;
    __syncthreads();
    int ee = (ent[2*(size_t)t*977]>>7)&0xFF;
    if(ee>=120 && ee<=133) atomicAdd(&c[0],1);
    if(t<32 && prop[2*t+1]==0u) atomicAdd(&c[1],1);
    for(int z=t; z<BATCH*RN; z+=256) g_ssum[z] = 0.f;
    __syncthreads();
    if(t==0){
        g_ftype = (c[0]>=200) ? 1 : 0;
        g_i64   = (c[1]>=30) ? 1 : 0;
    }
}

// ---------------- Kernel 1: gather + l2-normalize rows ----------------
__global__ void k_norm(const void* __restrict__ ent, const void* __restrict__ rule,
                       const void* __restrict__ prop, const void* __restrict__ val){
    int row = blockIdx.x*4 + (threadIdx.x>>6);
    int l = threadIdx.x & 63;
    const void* src; size_t off; float* dst;
    if(row < 1600){ src = ent; off = (size_t)LDI(prop,row)*DIM; dst = g_p + (size_t)row*DIM; }
    else if(row < 3200){ int i=row-1600; src = ent; off = (size_t)LDI(val,i)*DIM; dst = g_v + (size_t)i*DIM; }
    else if(row < 3456){ int i=row-3200; src = rule; off = (size_t)i*DIM; dst = g_re + (size_t)i*DIM; }
    else { int i=row-3456; src = ent; off = (size_t)i*DIM; dst = g_prop + (size_t)i*DIM; }
    float a = LD(src, off+l), b = LD(src, off+l+64);
    float n = fmaxf(sqrtf((float)wredd((double)a*a+(double)b*b)), 1e-12f);
    dst[l] = a/n; dst[l+64] = b/n;
}

// ---------------- Kernel 2: row matmuls ----------------
__global__ void k_mm(const void* __restrict__ fc1w, const void* __restrict__ fc2w, const void* __restrict__ fc3w,
                     const void* __restrict__ fc1b, const void* __restrict__ fc2b, const void* __restrict__ fc3b){
    __shared__ float row[DIM];
    int blk = blockIdx.x, j = threadIdx.x;
    const float* in; const void* w; size_t woff = 0; float bias = 0.f; float* out;
    if(blk < 1600){ in=g_p+(size_t)blk*DIM; w=fc1w; out=g_pa+(size_t)blk*DIM; }
    else if(blk < 3200){ int i=blk-1600; in=g_p+(size_t)i*DIM; w=fc2w; out=g_pb+(size_t)i*DIM; }
    else if(blk < 4800){ int i=blk-3200; in=g_p+(size_t)i*DIM; w=fc3w; out=g_pc+(size_t)i*DIM; }
    else if(blk < 5056){ int i=blk-4800; in=g_re+(size_t)i*DIM; w=fc1w; woff=DIM*DIM; out=g_ra+(size_t)i*DIM; bias=LD(fc1b,j); }
    else if(blk < 5312){ int i=blk-5056; in=g_re+(size_t)i*DIM; w=fc2w; woff=DIM*DIM; out=g_rb+(size_t)i*DIM; bias=LD(fc2b,j); }
    else if(blk < 5568){ int i=blk-5312; in=g_re+(size_t)i*DIM; w=fc3w; woff=DIM*DIM; out=g_rc+(size_t)i*DIM; bias=LD(fc3b,j); }
    else { int i=blk-5568; in=g_prop+(size_t)i*DIM; w=fc1w; out=g_pp1+(size_t)i*DIM; }
    row[j] = in[j];
    __syncthreads();
    double acc = (double)bias;
    for(int k=0;k<DIM;k++) acc += (double)row[k]*(double)LD(w, woff + (size_t)k*DIM + j);
    out[j] = (float)acc;
}

// ---------------- Kernel 3: pi -> rule_mask + reg partials (fp64 gates) ----------------
__global__ void k_pi(const void* __restrict__ fc4w, const void* __restrict__ fc4b){
    int r = blockIdx.x, w = threadIdx.x>>6, l = threadIdx.x&63;
    double b4 = (double)LD(fc4b,0);
    float ral = g_ra[r*DIM+l], rah = g_ra[r*DIM+l+64];
    double f4l = (double)LD(fc4w,l), f4h = (double)LD(fc4w,l+64);
    double mask_acc = 0.0, reg_acc = 0.0;
    for(int p = w; p < PN; p += 4){
        double a = (double)fmaxf(g_pp1[p*DIM+l]+ral,0.f)*f4l
                 + (double)fmaxf(g_pp1[p*DIM+l+64]+rah,0.f)*f4h;
        double piv = sigmd(wredd(a) + b4);
        if(l==0){
            if(piv > 0.5) mask_acc += piv;
            double eff = (p==r)? piv : (1.0-piv);
            double wgt = (p==r)? (double)RN : 1.0;
            reg_acc += -log(eff+1e-8)*wgt;
        }
    }
    __shared__ double sm[4], sr[4];
    if(l==0){ sm[w]=mask_acc; sr[w]=reg_acc; }
    __syncthreads();
    if(threadIdx.x==0){
        g_rmask[r] = (float)(1.0 + sm[0]+sm[1]+sm[2]+sm[3]);
        g_regp[r]  = (float)(sr[0]+sr[1]+sr[2]+sr[3]);
    }
}

// ---------------- Kernel 4: pack fc6 into MFMA B-fragments (bf16) ----------------
// B[k][n] for mfma_f32_16x16x32_bf16: lane holds k=quad*8+j, n=lane&15.
__global__ void k_prep(const void* __restrict__ fc6w){
    int t = threadIdx.x;
    for(int idx=t; idx<2048; idx+=256){
        int nt = idx>>8, ks=(idx>>6)&3, lane=idx&63;
        int n  = nt*16 + (lane&15);
        int k0 = ks*32 + (lane>>4)*8;
        short8 v;
#pragma unroll
        for(int j=0;j<8;j++) v[j] = f2bf(LD(fc6w,(size_t)(k0+j)*DIM + n));
        g_bfrag[nt][ks][lane] = v;
    }
}

// ---------------- Kernel 5: main fused scoring via MFMA ----------------
// block = (b, pv, rtile of 16 rules); 4 waves each own 32 output columns.
__global__ __launch_bounds__(256) void k_main(
    const void* __restrict__ fc4w, const void* __restrict__ fc4b,
    const void* __restrict__ fc5w, const void* __restrict__ fc5b,
    const void* __restrict__ fc6b,
    const void* __restrict__ same, const void* __restrict__ pad){
    __shared__ float s_rc[16*132];          // rc tile, stride 132 (bank-safe)
    __shared__ float s_pc[DIM];
    __shared__ float s_stats[16][4][2];     // [row][wave][ss,dv]
    __shared__ float s_s1[16], s_g1[16], s_p[16];
    __shared__ float s_misc[3];             // nvb, same, pad
    const int blk = blockIdx.x;
    const int b   = blk / 800;
    const int rem = blk % 800;
    const int pv  = rem / 16;
    const int rt  = rem % 16;
    const int r0  = rt*16;
    const size_t i = (size_t)b*MAXPV + pv;
    const int tid = threadIdx.x, w = tid>>6, l = tid&63;

    // stage rc tile + pc row
    for(int t=tid; t<16*DIM; t+=256){
        int rr = t>>7, kk = t&127;
        s_rc[rr*132 + kk] = g_rc[(size_t)(r0+rr)*DIM + kk];
    }
    if(tid < DIM) s_pc[tid] = g_pc[i*DIM + tid];

    // phase 0: gates (wave w -> rows mm*4+w), nvb, same/pad
    {
        const float f4l = LD(fc4w,l), f4h = LD(fc4w,l+64);
        const float f5l = LD(fc5w,l), f5h = LD(fc5w,l+64);
        const double b4 = (double)LD(fc4b,0);
        const float b5 = LD(fc5b,0);
        const float pal = g_pa[i*DIM+l], pah = g_pa[i*DIM+l+64];
        const float pbl = g_pb[i*DIM+l], pbh = g_pb[i*DIM+l+64];
#pragma unroll
        for(int mm=0; mm<4; mm++){
            int m = mm*4 + w, r = r0 + m;
            float h1l = fmaxf(pal + g_ra[(size_t)r*DIM+l],   0.f);
            float h1h = fmaxf(pah + g_ra[(size_t)r*DIM+l+64],0.f);
            double s1 = sigmd(wredd((double)h1l*f4l + (double)h1h*f4h) + b4);
            float h2l = fmaxf(pbl + g_rb[(size_t)r*DIM+l],   0.f);
            float h2h = fmaxf(pbh + g_rb[(size_t)r*DIM+l+64],0.f);
            float pp  = sigm(wred(h2l*f5l + h2h*f5h) + b5);
            if(l==0){ s_s1[m]=(float)s1; s_g1[m]=(s1>0.5)?1.f:0.f; s_p[m]=pp; }
        }
        if(w==0){
            float vl = g_v[i*DIM+l], vh = g_v[i*DIM+l+64];
            float nv = wred(vl*vl+vh*vh);
            if(l==0) s_misc[0] = sqrtf(nv);
        }
        if(tid==0){ s_misc[1]=(float)LDI(same,i); s_misc[2]=(float)LDI(pad,i); }
    }
    __syncthreads();

    // phase 1: MFMA K-loop (A = relu(pc+rc) built on the fly in bf16)
    f32x4 acc0 = {0.f,0.f,0.f,0.f}, acc1 = {0.f,0.f,0.f,0.f};
    const int am = l&15, quad = l>>4;
#pragma unroll
    for(int ks=0; ks<4; ks++){
        const int k0 = ks*32 + quad*8;
        const float* rcp = &s_rc[am*132 + k0];
        const float* pcp = &s_pc[k0];
        short8 a;
#pragma unroll
        for(int j=0;j<8;j++) a[j] = f2bf(fmaxf(pcp[j] + rcp[j], 0.f));
        short8 b0 = g_bfrag[2*w][ks][l];
        short8 b1 = g_bfrag[2*w+1][ks][l];
        acc0 = __builtin_amdgcn_mfma_f32_16x16x32_bf16(a, b0, acc0, 0,0,0);
        acc1 = __builtin_amdgcn_mfma_f32_16x16x32_bf16(a, b1, acc1, 0,0,0);
    }

    // phase 2: per-row ||x||^2 and v.x partials (this wave's 32 columns)
    {
        const int n0 = 32*w + am, n1 = n0 + 16;
        const float b60 = LD(fc6b,n0), b61 = LD(fc6b,n1);
        const float v0 = g_v[i*DIM+n0], v1 = g_v[i*DIM+n1];
#pragma unroll
        for(int q=0;q<4;q++){
            float x0 = acc0[q] + b60;
            float x1 = acc1[q] + b61;
            float ss = x0*x0 + x1*x1;
            float dv = x0*v0 + x1*v1;
#pragma unroll
            for(int o=1;o<16;o<<=1){ ss += __shfl_xor(ss,o,64); dv += __shfl_xor(dv,o,64); }
            if(am==0){
                int row = quad*4 + q;
                s_stats[row][w][0] = ss;
                s_stats[row][w][1] = dv;
            }
        }
    }
    __syncthreads();

    // phase 3: finalize 16 rows -> atomic score accumulate
    if(tid < 16){
        int row = tid, r = r0 + row;
        float ss = s_stats[row][0][0]+s_stats[row][1][0]+s_stats[row][2][0]+s_stats[row][3][0];
        float dv = s_stats[row][0][1]+s_stats[row][1][1]+s_stats[row][2][1]+s_stats[row][3][1];
        float nvb = s_misc[0];
        float nx = sqrtf(ss);
        float clipnx = fmaxf(nx, 1e-12f);
        float gvn = nx/clipnx;
        float denom = fmaxf(nvb*gvn, 1e-8f);
        float cosv = (dv/clipnx)/denom;
        float s2 = 0.5f*cosv + 0.5f;
        float pp = s_p[row];
        float sc = pp + (1.f-pp)*s2;
        float s1 = s_s1[row];
        sc = (s_misc[1]==1.f) ? s1*sc : (1.f - s1);
        sc *= s_misc[2];
        sc *= s_g1[row];
        atomicAdd(&g_ssum[b*RN + r], sc);
    }
}

// ---------------- Kernel 6: pooled max + reg mean -> FLOAT32 out ----------------
__global__ void k_fin(float* __restrict__ out){
    int w = threadIdx.x>>6, l = threadIdx.x&63;
#pragma unroll
    for(int i=0;i<8;i++){
        int b = w*8+i;
        float m = -1e30f;
        for(int rr=l; rr<RN; rr+=64) m = fmaxf(m, g_ssum[b*RN+rr] / g_rmask[rr]);
        m = wmax(m);
        if(l==0) out[b] = m;
    }
    __shared__ float s[4];
    float v = g_regp[threadIdx.x & 255];
    v = wred(v);
    if(l==0) s[w]=v;
    __syncthreads();
    if(threadIdx.x==0) out[32] = (s[0]+s[1]+s[2]+s[3]) / (float)(RN*PN);
}

extern "C" void kernel_launch(void* const* d_in, const int* in_sizes, int n_in,
                              void* d_out, int out_size, void* d_ws, size_t ws_size,
                              hipStream_t stream){
    // host-side input-order resolution via in_sizes (inactive under dict order)
    int map[18]; for(int i=0;i<18;i++) map[i]=i;
    if(n_in>=18 && in_sizes[0]==6400000){
        const int a[18] = {14,17,16,13,15,0,2,1,4,3,6,5,8,7,10,9,12,11};
        for(int i=0;i<18;i++) map[i]=a[i];
    }
    const void* prop = d_in[map[0]];
    const void* val  = d_in[map[1]];
    const void* same = d_in[map[2]];
    const void* pad  = d_in[map[3]];
    const void* rule = d_in[map[4]];
    const void* ent  = d_in[map[5]];
    const void* fc1w = d_in[map[6]];
    const void* fc1b = d_in[map[7]];
    const void* fc2w = d_in[map[8]];
    const void* fc2b = d_in[map[9]];
    const void* fc3w = d_in[map[10]];
    const void* fc3b = d_in[map[11]];
    const void* fc4w = d_in[map[12]];
    const void* fc4b = d_in[map[13]];
    const void* fc5w = d_in[map[14]];
    const void* fc5b = d_in[map[15]];
    const void* fc6w = d_in[map[16]];
    const void* fc6b = d_in[map[17]];

    k_detect<<<1, 256, 0, stream>>>((const u16*)ent, (const unsigned*)prop);
    k_norm<<<928, 256, 0, stream>>>(ent, rule, prop, val);
    k_mm<<<5824, 128, 0, stream>>>(fc1w, fc2w, fc3w, fc1b, fc2b, fc3b);
    k_pi<<<RN, 256, 0, stream>>>(fc4w, fc4b);
    k_prep<<<1, 256, 0, stream>>>(fc6w);
    k_main<<<BATCH*MAXPV*16, 256, 0, stream>>>(fc4w, fc4b, fc5w, fc5b, fc6b, same, pad);
    k_fin<<<1, 256, 0, stream>>>((float*)d_out);
}

// Round 10
// 280.806 us; speedup vs baseline: 10.1611x; 1.3557x over previous
//
#include <hip/hip_runtime.h>
#include <hip/hip_bf16.h>

#define BATCH 32
#define MAXPV 50
#define RN 256
#define PN 256
#define DIM 128
#define NPV (BATCH*MAXPV*DIM)
#define NI (BATCH*MAXPV)   // 1600 (b,pv) pairs

typedef unsigned short u16;
typedef __attribute__((ext_vector_type(8))) short short8;
typedef __attribute__((ext_vector_type(4))) float f32x4;

// ---- all intermediates in the code object ----
__device__ float g_p[NPV], g_v[NPV], g_pa[NPV], g_pb[NPV], g_pc[NPV];
__device__ float g_ra[RN*DIM], g_rb[RN*DIM], g_rc[RN*DIM], g_pp1[PN*DIM];
__device__ float g_prop[PN*DIM], g_re[RN*DIM];
__device__ float g_raT[DIM*RN], g_rbT[DIM*RN];       // transposed [k][r]
__device__ float2 g_s1p[NI*RN];                      // (s1 signed by gate, p)
__device__ float g_piv[PN*RN];                       // pi signed by gate
__device__ float g_rmask[RN], g_regp[RN], g_ssum[BATCH*RN];
__device__ short8 g_bfrag[8][4][64];                 // fc6 B-frags [nt][ks][lane]
__device__ int   g_ftype, g_i64;

__device__ __forceinline__ float bf2f(u16 u){ return __uint_as_float(((unsigned)u)<<16); }
__device__ __forceinline__ float LD(const void* p, size_t i){
    return g_ftype ? bf2f(((const u16*)p)[i]) : ((const float*)p)[i];
}
__device__ __forceinline__ int LDI(const void* p, size_t i){
    return g_i64 ? (int)((const long long*)p)[i] : ((const int*)p)[i];
}
__device__ __forceinline__ short f2bf(float f){
    unsigned u = __float_as_uint(f);
    u = (u + 0x7FFFu + ((u>>16)&1u)) >> 16;
    return (short)u;
}
__device__ __forceinline__ float wred(float v){
#pragma unroll
    for(int o=32;o;o>>=1) v += __shfl_xor(v,o,64);
    return v;
}
__device__ __forceinline__ double wredd(double v){
#pragma unroll
    for(int o=32;o;o>>=1) v += __shfl_xor(v,o,64);
    return v;
}
__device__ __forceinline__ float wmax(float v){
#pragma unroll
    for(int o=32;o;o>>=1) v = fmaxf(v,__shfl_xor(v,o,64));
    return v;
}
__device__ __forceinline__ float sigm(float x){ return 1.f/(1.f+expf(-x)); }

// ---------------- K0: dtype detect + zero accumulators ----------------
__global__ void k_detect(const u16* __restrict__ ent, const unsigned* __restrict__ prop){
    __shared__ int c[2];
    int t = threadIdx.x;
    if(t<2) c[t]=0;
    __syncthreads();
    int ee = (ent[2*(size_t)t*977]>>7)&0xFF;
    if(ee>=120 && ee<=133) atomicAdd(&c[0],1);
    if(t<32 && prop[2*t+1]==0u) atomicAdd(&c[1],1);
    for(int z=t; z<BATCH*RN; z+=256) g_ssum[z]=0.f;
    __syncthreads();
    if(t==0){ g_ftype = (c[0]>=200)?1:0; g_i64 = (c[1]>=30)?1:0; }
}

// ---------------- K1: gather + l2-normalize ----------------
__global__ void k_norm(const void* __restrict__ ent, const void* __restrict__ rule,
                       const void* __restrict__ prop, const void* __restrict__ val){
    int row = blockIdx.x*4 + (threadIdx.x>>6);
    int l = threadIdx.x & 63;
    const void* src; size_t off; float* dst;
    if(row < 1600){ src=ent; off=(size_t)LDI(prop,row)*DIM; dst=g_p+(size_t)row*DIM; }
    else if(row < 3200){ int i=row-1600; src=ent; off=(size_t)LDI(val,i)*DIM; dst=g_v+(size_t)i*DIM; }
    else if(row < 3456){ int i=row-3200; src=rule; off=(size_t)i*DIM; dst=g_re+(size_t)i*DIM; }
    else { int i=row-3456; src=ent; off=(size_t)i*DIM; dst=g_prop+(size_t)i*DIM; }
    float a = LD(src,off+l), b = LD(src,off+l+64);
    float n = fmaxf(sqrtf((float)wredd((double)a*a+(double)b*b)), 1e-12f);
    dst[l]=a/n; dst[l+64]=b/n;
}

// ---------------- K2: row matmuls (fp64 acc, proven exact) ----------------
__global__ void k_mm(const void* __restrict__ fc1w, const void* __restrict__ fc2w, const void* __restrict__ fc3w,
                     const void* __restrict__ fc1b, const void* __restrict__ fc2b, const void* __restrict__ fc3b){
    __shared__ float row[DIM];
    int blk = blockIdx.x, j = threadIdx.x;
    const float* in; const void* w; size_t woff=0; float bias=0.f; float* out;
    if(blk < 1600){ in=g_p+(size_t)blk*DIM; w=fc1w; out=g_pa+(size_t)blk*DIM; }
    else if(blk < 3200){ int i=blk-1600; in=g_p+(size_t)i*DIM; w=fc2w; out=g_pb+(size_t)i*DIM; }
    else if(blk < 4800){ int i=blk-3200; in=g_p+(size_t)i*DIM; w=fc3w; out=g_pc+(size_t)i*DIM; }
    else if(blk < 5056){ int i=blk-4800; in=g_re+(size_t)i*DIM; w=fc1w; woff=DIM*DIM; out=g_ra+(size_t)i*DIM; bias=LD(fc1b,j); }
    else if(blk < 5312){ int i=blk-5056; in=g_re+(size_t)i*DIM; w=fc2w; woff=DIM*DIM; out=g_rb+(size_t)i*DIM; bias=LD(fc2b,j); }
    else if(blk < 5568){ int i=blk-5312; in=g_re+(size_t)i*DIM; w=fc3w; woff=DIM*DIM; out=g_rc+(size_t)i*DIM; bias=LD(fc3b,j); }
    else { int i=blk-5568; in=g_prop+(size_t)i*DIM; w=fc1w; out=g_pp1+(size_t)i*DIM; }
    row[j]=in[j];
    __syncthreads();
    double acc = (double)bias;
    for(int k=0;k<DIM;k++) acc += (double)row[k]*(double)LD(w, woff+(size_t)k*DIM+j);
    out[j]=(float)acc;
}

// ---------------- K3: pack fc6 B-frags + transpose ra/rb ----------------
__global__ void k_prep(const void* __restrict__ fc6w){
    int blk = blockIdx.x, tid = threadIdx.x;
    if(blk == 64){
        for(int idx=tid; idx<2048; idx+=256){
            int nt=idx>>8, ks=(idx>>6)&3, lane=idx&63;
            int n = nt*16 + (lane&15);
            int k0 = ks*32 + (lane>>4)*8;
            short8 v;
#pragma unroll
            for(int j=0;j<8;j++) v[j] = f2bf(LD(fc6w,(size_t)(k0+j)*DIM + n));
            g_bfrag[nt][ks][lane] = v;
        }
    } else {
        int idx0 = blk*256 + tid;
#pragma unroll
        for(int n=0;n<4;n++){
            int idx = idx0 + n*16384;            // 65536 total
            int which = idx>>15;
            int k = (idx>>8)&127, r = idx&255;
            if(which) g_rbT[k*256+r] = g_rb[(size_t)r*DIM+k];
            else      g_raT[k*256+r] = g_ra[(size_t)r*DIM+k];
        }
    }
}

// ---------------- K4: gates (r-parallel, fp64 dot sign, fp32 value) ----------------
// blocks 0..1599: (b,pv)-rows -> s1,p ; blocks 1600..1855: prop-rows -> pi
__global__ __launch_bounds__(256) void k_gate(
    const void* __restrict__ fc4w, const void* __restrict__ fc4b,
    const void* __restrict__ fc5w, const void* __restrict__ fc5b){
    __shared__ float s_a[DIM], s_b[DIM], s_f5[DIM];
    __shared__ double s_f4[DIM];
    const int blk = blockIdx.x, tid = threadIdx.x;
    const bool typeA = blk < NI;
    const float* arow = typeA ? g_pa + (size_t)blk*DIM : g_pp1 + (size_t)(blk-NI)*DIM;
    if(tid<DIM){ s_a[tid]=arow[tid]; s_f4[tid]=(double)LD(fc4w,tid); }
    else { int t=tid-DIM; if(typeA) s_b[t]=g_pb[(size_t)blk*DIM+t]; s_f5[t]=LD(fc5w,t); }
    __syncthreads();
    const int r = tid;
    double d1 = 0.0; float pacc = 0.f;
    if(typeA){
#pragma unroll 4
        for(int k=0;k<DIM;k++){
            float a1 = fmaxf(s_a[k] + g_raT[k*256+r], 0.f);
            d1 += (double)a1 * s_f4[k];
            float b1 = fmaxf(s_b[k] + g_rbT[k*256+r], 0.f);
            pacc = fmaf(b1, s_f5[k], pacc);
        }
    } else {
#pragma unroll 4
        for(int k=0;k<DIM;k++){
            float a1 = fmaxf(s_a[k] + g_raT[k*256+r], 0.f);
            d1 += (double)a1 * s_f4[k];
        }
    }
    double sd = d1 + (double)LD(fc4b,0);
    bool gate = sd > 0.0;                        // sigm(sd)>0.5 <=> sd>0
    float s1v = 1.f/(1.f+expf(-(float)sd));
    if(typeA){
        float p = 1.f/(1.f+expf(-(pacc + LD(fc5b,0))));
        float2 o; o.x = gate ? s1v : -s1v; o.y = p;
        g_s1p[(size_t)blk*RN + r] = o;
    } else {
        g_piv[(size_t)(blk-NI)*RN + r] = gate ? s1v : -s1v;
    }
}

// ---------------- K5: reduce pi -> rule_mask + reg ----------------
__global__ void k_pired(){
    const int r = blockIdx.x, tid = threadIdx.x;
    float v = g_piv[(size_t)tid*RN + r];
    float piv = fabsf(v);
    float m = (v > 0.f) ? piv : 0.f;
    float eff = (tid==r) ? piv : (1.f - piv);
    float wgt = (tid==r) ? (float)RN : 1.f;
    float rg = -logf(eff + 1e-8f)*wgt;
    int w = tid>>6, l = tid&63;
    m = wred(m); rg = wred(rg);
    __shared__ float sm[4], sg[4];
    if(l==0){ sm[w]=m; sg[w]=rg; }
    __syncthreads();
    if(tid==0){
        g_rmask[r] = 1.f + sm[0]+sm[1]+sm[2]+sm[3];
        g_regp[r]  = sg[0]+sg[1]+sg[2]+sg[3];
    }
}

// ---------------- K6: main MFMA scoring, block=(b,pv), M=256 N=128 K=128 ----------------
__global__ __launch_bounds__(256) void k_main(
    const void* __restrict__ fc6b,
    const void* __restrict__ same, const void* __restrict__ pad){
    __shared__ float s_pc[DIM];
    __shared__ float s_misc[3];                  // nvb, same, pad
    const int i = blockIdx.x;                    // (b,pv)
    const int b = i / MAXPV;
    const int tid = threadIdx.x, w = tid>>6, l = tid&63;
    const int am = l&15, quad = l>>4;

    if(tid < DIM) s_pc[tid] = g_pc[(size_t)i*DIM + tid];
    else if(tid < 192){                          // wave 2: ||v||
        int t = tid-128;
        float vl = g_v[(size_t)i*DIM+t], vh = g_v[(size_t)i*DIM+t+64];
        float nv = 0.f;
        // reduce within this wave (64 lanes)
        nv = vl*vl + vh*vh;
#pragma unroll
        for(int o=32;o;o>>=1) nv += __shfl_xor(nv,o,64);
        if(t==0) s_misc[0] = sqrtf(nv);
    } else if(tid == 192){
        s_misc[1] = (float)LDI(same,i);
        s_misc[2] = (float)LDI(pad,i);
    }
    __syncthreads();

    // hoisted per-lane column data (n = nt*16 + am)
    float v8[8], b68[8];
#pragma unroll
    for(int nt=0; nt<8; nt++){
        v8[nt]  = g_v[(size_t)i*DIM + nt*16 + am];
        b68[nt] = LD(fc6b, nt*16 + am);
    }
    const float nvb = s_misc[0], samef = s_misc[1], padf = s_misc[2];

    for(int mt=0; mt<4; mt++){
        const int r0 = (w*4 + mt)*16;
        // build A-frags for this 16-rule tile: a[ks], lane holds A[am][ks*32+quad*8+j]
        short8 a[4];
#pragma unroll
        for(int ks=0; ks<4; ks++){
            const int k0 = ks*32 + quad*8;
            const float4 c0 = *(const float4*)&g_rc[(size_t)(r0+am)*DIM + k0];
            const float4 c1 = *(const float4*)&g_rc[(size_t)(r0+am)*DIM + k0 + 4];
            const float4 p0 = *(const float4*)&s_pc[k0];
            const float4 p1 = *(const float4*)&s_pc[k0+4];
            short8 t;
            t[0]=f2bf(fmaxf(p0.x+c0.x,0.f)); t[1]=f2bf(fmaxf(p0.y+c0.y,0.f));
            t[2]=f2bf(fmaxf(p0.z+c0.z,0.f)); t[3]=f2bf(fmaxf(p0.w+c0.w,0.f));
            t[4]=f2bf(fmaxf(p1.x+c1.x,0.f)); t[5]=f2bf(fmaxf(p1.y+c1.y,0.f));
            t[6]=f2bf(fmaxf(p1.z+c1.z,0.f)); t[7]=f2bf(fmaxf(p1.w+c1.w,0.f));
            a[ks]=t;
        }
        // GEMM: 8 n-tiles x 4 ksteps
        f32x4 acc[8];
#pragma unroll
        for(int nt=0; nt<8; nt++){ acc[nt][0]=0.f; acc[nt][1]=0.f; acc[nt][2]=0.f; acc[nt][3]=0.f; }
#pragma unroll
        for(int nt=0; nt<8; nt++){
#pragma unroll
            for(int ks=0; ks<4; ks++){
                short8 bf = g_bfrag[nt][ks][l];
                acc[nt] = __builtin_amdgcn_mfma_f32_16x16x32_bf16(a[ks], bf, acc[nt], 0,0,0);
            }
        }
        // epilogue: rows row=quad*4+q; reduce over am lanes
#pragma unroll
        for(int q=0; q<4; q++){
            float ss=0.f, dv=0.f;
#pragma unroll
            for(int nt=0; nt<8; nt++){
                float x = acc[nt][q] + b68[nt];
                ss = fmaf(x,x,ss);
                dv = fmaf(x,v8[nt],dv);
            }
#pragma unroll
            for(int o=1;o<16;o<<=1){ ss += __shfl_xor(ss,o,64); dv += __shfl_xor(dv,o,64); }
            if(am==0){
                int r = r0 + quad*4 + q;
                float2 sp = g_s1p[(size_t)i*RN + r];
                float s1 = fabsf(sp.x);
                float gate = (sp.x > 0.f) ? 1.f : 0.f;
                float pp = sp.y;
                float nx = sqrtf(ss);
                float clipnx = fmaxf(nx, 1e-12f);
                float gvn = nx/clipnx;
                float denom = fmaxf(nvb*gvn, 1e-8f);
                float cosv = (dv/clipnx)/denom;
                float s2 = 0.5f*cosv + 0.5f;
                float sc = pp + (1.f-pp)*s2;
                sc = (samef==1.f) ? s1*sc : (1.f - s1);
                sc *= padf * gate;
                atomicAdd(&g_ssum[b*RN + r], sc);
            }
        }
    }
}

// ---------------- K7: pooled max + reg mean -> fp32 out ----------------
__global__ void k_fin(float* __restrict__ out){
    int w = threadIdx.x>>6, l = threadIdx.x&63;
#pragma unroll
    for(int i=0;i<8;i++){
        int b = w*8+i;
        float m = -1e30f;
        for(int rr=l; rr<RN; rr+=64) m = fmaxf(m, g_ssum[b*RN+rr] / g_rmask[rr]);
        m = wmax(m);
        if(l==0) out[b] = m;
    }
    __shared__ float s[4];
    float v = g_regp[threadIdx.x & 255];
    v = wred(v);
    if(l==0) s[w]=v;
    __syncthreads();
    if(threadIdx.x==0) out[32] = (s[0]+s[1]+s[2]+s[3]) / (float)(RN*PN);
}

extern "C" void kernel_launch(void* const* d_in, const int* in_sizes, int n_in,
                              void* d_out, int out_size, void* d_ws, size_t ws_size,
                              hipStream_t stream){
    int map[18]; for(int i=0;i<18;i++) map[i]=i;
    if(n_in>=18 && in_sizes[0]==6400000){
        const int a[18] = {14,17,16,13,15,0,2,1,4,3,6,5,8,7,10,9,12,11};
        for(int i=0;i<18;i++) map[i]=a[i];
    }
    const void* prop = d_in[map[0]];
    const void* val  = d_in[map[1]];
    const void* same = d_in[map[2]];
    const void* pad  = d_in[map[3]];
    const void* rule = d_in[map[4]];
    const void* ent  = d_in[map[5]];
    const void* fc1w = d_in[map[6]];
    const void* fc1b = d_in[map[7]];
    const void* fc2w = d_in[map[8]];
    const void* fc2b = d_in[map[9]];
    const void* fc3w = d_in[map[10]];
    const void* fc3b = d_in[map[11]];
    const void* fc4w = d_in[map[12]];
    const void* fc4b = d_in[map[13]];
    const void* fc5w = d_in[map[14]];
    const void* fc5b = d_in[map[15]];
    const void* fc6w = d_in[map[16]];
    const void* fc6b = d_in[map[17]];

    k_detect<<<1, 256, 0, stream>>>((const u16*)ent, (const unsigned*)prop);
    k_norm<<<928, 256, 0, stream>>>(ent, rule, prop, val);
    k_mm<<<5824, 128, 0, stream>>>(fc1w, fc2w, fc3w, fc1b, fc2b, fc3b);
    k_prep<<<65, 256, 0, stream>>>(fc6w);
    k_gate<<<NI+PN, 256, 0, stream>>>(fc4w, fc4b, fc5w, fc5b);
    k_pired<<<RN, 256, 0, stream>>>();
    k_main<<<NI, 256, 0, stream>>>(fc6b, same, pad);
    k_fin<<<1, 256, 0, stream>>>((float*)d_out);
}

// Round 11
// 227.170 us; speedup vs baseline: 12.5601x; 1.2361x over previous
//
#include <hip/hip_runtime.h>
#include <hip/hip_bf16.h>

#define BATCH 32
#define MAXPV 50
#define RN 256
#define PN 256
#define DIM 128
#define NPV (BATCH*MAXPV*DIM)
#define NI (BATCH*MAXPV)   // 1600 (b,pv) pairs

typedef unsigned short u16;
typedef __attribute__((ext_vector_type(8))) short short8;
typedef __attribute__((ext_vector_type(4))) float f32x4;

// ---- all intermediates in the code object ----
__device__ float g_p[NPV], g_v[NPV], g_pa[NPV], g_pb[NPV], g_pc[NPV];
__device__ float g_ra[RN*DIM], g_rb[RN*DIM], g_rc[RN*DIM], g_pp1[PN*DIM];
__device__ float g_prop[PN*DIM], g_re[RN*DIM];
__device__ float g_raT[DIM*RN], g_rbT[DIM*RN];       // transposed [k][r]
__device__ float2 g_s1p[NI*RN];                      // (s1 signed by gate, p)
__device__ float g_piv[PN*RN];                       // pi signed by gate
__device__ float g_rmask[RN], g_regp[RN];
__device__ float g_scores[(size_t)NI*RN];            // per-(i,r) gated score
__device__ short8 g_bfrag[8][4][64];                 // fc6 B-frags [nt][ks][lane]
__device__ int   g_ftype, g_i64;

__device__ __forceinline__ float bf2f(u16 u){ return __uint_as_float(((unsigned)u)<<16); }
__device__ __forceinline__ float LD(const void* p, size_t i){
    return g_ftype ? bf2f(((const u16*)p)[i]) : ((const float*)p)[i];
}
__device__ __forceinline__ int LDI(const void* p, size_t i){
    return g_i64 ? (int)((const long long*)p)[i] : ((const int*)p)[i];
}
__device__ __forceinline__ short f2bf(float f){
    unsigned u = __float_as_uint(f);
    u = (u + 0x7FFFu + ((u>>16)&1u)) >> 16;
    return (short)u;
}
__device__ __forceinline__ float wred(float v){
#pragma unroll
    for(int o=32;o;o>>=1) v += __shfl_xor(v,o,64);
    return v;
}
__device__ __forceinline__ double wredd(double v){
#pragma unroll
    for(int o=32;o;o>>=1) v += __shfl_xor(v,o,64);
    return v;
}
__device__ __forceinline__ float wmax(float v){
#pragma unroll
    for(int o=32;o;o>>=1) v = fmaxf(v,__shfl_xor(v,o,64));
    return v;
}

// ---------------- K0: dtype detect ----------------
__global__ void k_detect(const u16* __restrict__ ent, const unsigned* __restrict__ prop){
    __shared__ int c[2];
    int t = threadIdx.x;
    if(t<2) c[t]=0;
    __syncthreads();
    int ee = (ent[2*(size_t)t*977]>>7)&0xFF;
    if(ee>=120 && ee<=133) atomicAdd(&c[0],1);
    if(t<32 && prop[2*t+1]==0u) atomicAdd(&c[1],1);
    __syncthreads();
    if(t==0){ g_ftype = (c[0]>=200)?1:0; g_i64 = (c[1]>=30)?1:0; }
}

// ---------------- K1: gather + l2-normalize ----------------
__global__ void k_norm(const void* __restrict__ ent, const void* __restrict__ rule,
                       const void* __restrict__ prop, const void* __restrict__ val){
    int row = blockIdx.x*4 + (threadIdx.x>>6);
    int l = threadIdx.x & 63;
    const void* src; size_t off; float* dst;
    if(row < 1600){ src=ent; off=(size_t)LDI(prop,row)*DIM; dst=g_p+(size_t)row*DIM; }
    else if(row < 3200){ int i=row-1600; src=ent; off=(size_t)LDI(val,i)*DIM; dst=g_v+(size_t)i*DIM; }
    else if(row < 3456){ int i=row-3200; src=rule; off=(size_t)i*DIM; dst=g_re+(size_t)i*DIM; }
    else { int i=row-3456; src=ent; off=(size_t)i*DIM; dst=g_prop+(size_t)i*DIM; }
    float a = LD(src,off+l), b = LD(src,off+l+64);
    float n = fmaxf(sqrtf((float)wredd((double)a*a+(double)b*b)), 1e-12f);
    dst[l]=a/n; dst[l+64]=b/n;
}

// ---------------- K2: row matmuls (fp64, 4-way ILP) ----------------
__global__ void k_mm(const void* __restrict__ fc1w, const void* __restrict__ fc2w, const void* __restrict__ fc3w,
                     const void* __restrict__ fc1b, const void* __restrict__ fc2b, const void* __restrict__ fc3b){
    __shared__ float row[DIM];
    int blk = blockIdx.x, j = threadIdx.x;
    const float* in; const void* w; size_t woff=0; float bias=0.f; float* out;
    if(blk < 1600){ in=g_p+(size_t)blk*DIM; w=fc1w; out=g_pa+(size_t)blk*DIM; }
    else if(blk < 3200){ int i=blk-1600; in=g_p+(size_t)i*DIM; w=fc2w; out=g_pb+(size_t)i*DIM; }
    else if(blk < 4800){ int i=blk-3200; in=g_p+(size_t)i*DIM; w=fc3w; out=g_pc+(size_t)i*DIM; }
    else if(blk < 5056){ int i=blk-4800; in=g_re+(size_t)i*DIM; w=fc1w; woff=DIM*DIM; out=g_ra+(size_t)i*DIM; bias=LD(fc1b,j); }
    else if(blk < 5312){ int i=blk-5056; in=g_re+(size_t)i*DIM; w=fc2w; woff=DIM*DIM; out=g_rb+(size_t)i*DIM; bias=LD(fc2b,j); }
    else if(blk < 5568){ int i=blk-5312; in=g_re+(size_t)i*DIM; w=fc3w; woff=DIM*DIM; out=g_rc+(size_t)i*DIM; bias=LD(fc3b,j); }
    else { int i=blk-5568; in=g_prop+(size_t)i*DIM; w=fc1w; out=g_pp1+(size_t)i*DIM; }
    row[j]=in[j];
    __syncthreads();
    double a0=0.0, a1=0.0, a2=0.0, a3=0.0;
    for(int k=0;k<DIM;k+=4){
        a0 += (double)row[k  ]*(double)LD(w, woff+(size_t)(k  )*DIM+j);
        a1 += (double)row[k+1]*(double)LD(w, woff+(size_t)(k+1)*DIM+j);
        a2 += (double)row[k+2]*(double)LD(w, woff+(size_t)(k+2)*DIM+j);
        a3 += (double)row[k+3]*(double)LD(w, woff+(size_t)(k+3)*DIM+j);
    }
    out[j]=(float)((double)bias + ((a0+a1)+(a2+a3)));
}

// ---------------- K3: pack fc6 B-frags + transpose ra/rb ----------------
__global__ void k_prep(const void* __restrict__ fc6w){
    int blk = blockIdx.x, tid = threadIdx.x;
    if(blk == 64){
        for(int idx=tid; idx<2048; idx+=256){
            int nt=idx>>8, ks=(idx>>6)&3, lane=idx&63;
            int n = nt*16 + (lane&15);
            int k0 = ks*32 + (lane>>4)*8;
            short8 v;
#pragma unroll
            for(int j=0;j<8;j++) v[j] = f2bf(LD(fc6w,(size_t)(k0+j)*DIM + n));
            g_bfrag[nt][ks][lane] = v;
        }
    } else {
        int idx0 = blk*256 + tid;
#pragma unroll
        for(int n=0;n<4;n++){
            int idx = idx0 + n*16384;
            int which = idx>>15;
            int k = (idx>>8)&127, r = idx&255;
            if(which) g_rbT[k*256+r] = g_rb[(size_t)r*DIM+k];
            else      g_raT[k*256+r] = g_ra[(size_t)r*DIM+k];
        }
    }
}

// ---------------- K4: gates (r-parallel, fp64 dot sign, 2-way ILP) ----------------
__global__ __launch_bounds__(256) void k_gate(
    const void* __restrict__ fc4w, const void* __restrict__ fc4b,
    const void* __restrict__ fc5w, const void* __restrict__ fc5b){
    __shared__ float s_a[DIM], s_b[DIM], s_f5[DIM];
    __shared__ double s_f4[DIM];
    const int blk = blockIdx.x, tid = threadIdx.x;
    const bool typeA = blk < NI;
    const float* arow = typeA ? g_pa + (size_t)blk*DIM : g_pp1 + (size_t)(blk-NI)*DIM;
    if(tid<DIM){ s_a[tid]=arow[tid]; s_f4[tid]=(double)LD(fc4w,tid); }
    else { int t=tid-DIM; if(typeA) s_b[t]=g_pb[(size_t)blk*DIM+t]; s_f5[t]=LD(fc5w,t); }
    __syncthreads();
    const int r = tid;
    double d0=0.0, d1=0.0; float p0=0.f, p1=0.f;
    if(typeA){
        for(int k=0;k<DIM;k+=2){
            float a1 = fmaxf(s_a[k]   + g_raT[k*256+r],     0.f);
            float a2 = fmaxf(s_a[k+1] + g_raT[(k+1)*256+r], 0.f);
            d0 += (double)a1 * s_f4[k];
            d1 += (double)a2 * s_f4[k+1];
            float b1 = fmaxf(s_b[k]   + g_rbT[k*256+r],     0.f);
            float b2 = fmaxf(s_b[k+1] + g_rbT[(k+1)*256+r], 0.f);
            p0 = fmaf(b1, s_f5[k],   p0);
            p1 = fmaf(b2, s_f5[k+1], p1);
        }
    } else {
        for(int k=0;k<DIM;k+=2){
            float a1 = fmaxf(s_a[k]   + g_raT[k*256+r],     0.f);
            float a2 = fmaxf(s_a[k+1] + g_raT[(k+1)*256+r], 0.f);
            d0 += (double)a1 * s_f4[k];
            d1 += (double)a2 * s_f4[k+1];
        }
    }
    double sd = (d0+d1) + (double)LD(fc4b,0);
    bool gate = sd > 0.0;
    float s1v = 1.f/(1.f+expf(-(float)sd));
    if(typeA){
        float p = 1.f/(1.f+expf(-((p0+p1) + LD(fc5b,0))));
        float2 o; o.x = gate ? s1v : -s1v; o.y = p;
        g_s1p[(size_t)blk*RN + r] = o;
    } else {
        g_piv[(size_t)(blk-NI)*RN + r] = gate ? s1v : -s1v;
    }
}

// ---------------- K5: reduce pi -> rule_mask + reg ----------------
__global__ void k_pired(){
    const int r = blockIdx.x, tid = threadIdx.x;
    float v = g_piv[(size_t)tid*RN + r];
    float piv = fabsf(v);
    float m = (v > 0.f) ? piv : 0.f;
    float eff = (tid==r) ? piv : (1.f - piv);
    float wgt = (tid==r) ? (float)RN : 1.f;
    float rg = -logf(eff + 1e-8f)*wgt;
    int w = tid>>6, l = tid&63;
    m = wred(m); rg = wred(rg);
    __shared__ float sm[4], sg[4];
    if(l==0){ sm[w]=m; sg[w]=rg; }
    __syncthreads();
    if(tid==0){
        g_rmask[r] = 1.f + sm[0]+sm[1]+sm[2]+sm[3];
        g_regp[r]  = sg[0]+sg[1]+sg[2]+sg[3];
    }
}

// ---------------- K6: main MFMA scoring v3 ----------------
// block=(i), M=256 N=128 K=128. A staged in LDS per 64-row supertile (coalesced);
// B-frags hoisted to registers (2 n-tiles per wave); scores -> g_scores (no atomics).
__global__ __launch_bounds__(256) void k_main(
    const void* __restrict__ fc6b,
    const void* __restrict__ same, const void* __restrict__ pad){
    __shared__ short s_A[64*136];               // 64 rows x 128 cols bf16, stride 136
    __shared__ float s_st[64][4][2];            // per-row (ss,dv) partials per wave
    __shared__ float s_misc[3];                 // nvb, same, pad
    const int i = blockIdx.x;
    const int tid = threadIdx.x, w = tid>>6, l = tid&63;
    const int am = l&15, quad = l>>4;

    // hoists: pc slice for staging (col fixed per thread)
    const int col = (tid&15)*8;
    const float4 p0 = *(const float4*)&g_pc[(size_t)i*DIM + col];
    const float4 p1 = *(const float4*)&g_pc[(size_t)i*DIM + col + 4];
    // B-frags: wave w owns cols w*32 .. w*32+31 (n-tiles 2w, 2w+1)
    short8 bA[4], bB[4];
#pragma unroll
    for(int ks=0; ks<4; ks++){ bA[ks]=g_bfrag[2*w][ks][l]; bB[ks]=g_bfrag[2*w+1][ks][l]; }
    const int n0 = w*32 + am, n1 = n0 + 16;
    const float v0 = g_v[(size_t)i*DIM + n0], v1 = g_v[(size_t)i*DIM + n1];
    const float b60 = LD(fc6b, n0), b61 = LD(fc6b, n1);

    if(w==3){                                   // ||v|| (v pre-normalized; ~1)
        float vl = g_v[(size_t)i*DIM + l], vh = g_v[(size_t)i*DIM + l + 64];
        float nv = vl*vl + vh*vh;
#pragma unroll
        for(int o=32;o;o>>=1) nv += __shfl_xor(nv,o,64);
        if(l==0) s_misc[0] = sqrtf(nv);
    }
    if(tid==0){ s_misc[1]=(float)LDI(same,i); s_misc[2]=(float)LDI(pad,i); }

    for(int sup=0; sup<4; sup++){
        const int r0 = sup*64;
        // stage A = bf16(relu(pc + rc)) for rows r0..r0+63, coalesced
#pragma unroll
        for(int c=0;c<4;c++){
            const int row = c*16 + (tid>>4);
            const float4 c0 = *(const float4*)&g_rc[(size_t)(r0+row)*DIM + col];
            const float4 c1 = *(const float4*)&g_rc[(size_t)(r0+row)*DIM + col + 4];
            short8 t;
            t[0]=f2bf(fmaxf(p0.x+c0.x,0.f)); t[1]=f2bf(fmaxf(p0.y+c0.y,0.f));
            t[2]=f2bf(fmaxf(p0.z+c0.z,0.f)); t[3]=f2bf(fmaxf(p0.w+c0.w,0.f));
            t[4]=f2bf(fmaxf(p1.x+c1.x,0.f)); t[5]=f2bf(fmaxf(p1.y+c1.y,0.f));
            t[6]=f2bf(fmaxf(p1.z+c1.z,0.f)); t[7]=f2bf(fmaxf(p1.w+c1.w,0.f));
            *(short8*)&s_A[row*136 + col] = t;
        }
        __syncthreads();
        // compute 4 sub-tiles of 16 rows
#pragma unroll
        for(int sub=0; sub<4; sub++){
            short8 a[4];
#pragma unroll
            for(int ks=0; ks<4; ks++)
                a[ks] = *(const short8*)&s_A[(sub*16+am)*136 + ks*32 + quad*8];
            f32x4 acc0 = {0.f,0.f,0.f,0.f}, acc1 = {0.f,0.f,0.f,0.f};
#pragma unroll
            for(int ks=0; ks<4; ks++){
                acc0 = __builtin_amdgcn_mfma_f32_16x16x32_bf16(a[ks], bA[ks], acc0, 0,0,0);
                acc1 = __builtin_amdgcn_mfma_f32_16x16x32_bf16(a[ks], bB[ks], acc1, 0,0,0);
            }
#pragma unroll
            for(int q=0; q<4; q++){
                float x0 = acc0[q] + b60;
                float x1 = acc1[q] + b61;
                float ss = x0*x0 + x1*x1;
                float dv = x0*v0 + x1*v1;
#pragma unroll
                for(int o=1;o<16;o<<=1){ ss += __shfl_xor(ss,o,64); dv += __shfl_xor(dv,o,64); }
                if(am==0){
                    int row = sub*16 + quad*4 + q;
                    s_st[row][w][0] = ss;
                    s_st[row][w][1] = dv;
                }
            }
        }
        __syncthreads();
        // finalize 64 rows
        if(tid < 64){
            const int r = r0 + tid;
            float ss = s_st[tid][0][0]+s_st[tid][1][0]+s_st[tid][2][0]+s_st[tid][3][0];
            float dv = s_st[tid][0][1]+s_st[tid][1][1]+s_st[tid][2][1]+s_st[tid][3][1];
            float2 sp = g_s1p[(size_t)i*RN + r];
            float s1 = fabsf(sp.x);
            float gate = (sp.x > 0.f) ? 1.f : 0.f;
            float pp = sp.y;
            float nvb = s_misc[0];
            float nx = sqrtf(ss);
            float clipnx = fmaxf(nx, 1e-12f);
            float gvn = nx/clipnx;
            float denom = fmaxf(nvb*gvn, 1e-8f);
            float cosv = (dv/clipnx)/denom;
            float s2 = 0.5f*cosv + 0.5f;
            float sc = pp + (1.f-pp)*s2;
            sc = (s_misc[1]==1.f) ? s1*sc : (1.f - s1);
            sc *= s_misc[2] * gate;
            g_scores[(size_t)i*RN + r] = sc;
        }
        __syncthreads();
    }
}

// ---------------- K7: pooled max (per-b blocks) + reg mean ----------------
__global__ void k_fin(float* __restrict__ out){
    const int blk = blockIdx.x, tid = threadIdx.x;
    const int w = tid>>6, l = tid&63;
    __shared__ float s[4];
    if(blk < 32){
        float ssum = 0.f;
        for(int pv=0; pv<MAXPV; pv++)
            ssum += g_scores[((size_t)blk*MAXPV + pv)*RN + tid];
        float sc = ssum / g_rmask[tid];
        float m = wmax(sc);
        if(l==0) s[w]=m;
        __syncthreads();
        if(tid==0) out[blk] = fmaxf(fmaxf(s[0],s[1]), fmaxf(s[2],s[3]));
    } else {
        float v = g_regp[tid];
        v = wred(v);
        if(l==0) s[w]=v;
        __syncthreads();
        if(tid==0) out[32] = (s[0]+s[1]+s[2]+s[3]) / (float)(RN*PN);
    }
}

extern "C" void kernel_launch(void* const* d_in, const int* in_sizes, int n_in,
                              void* d_out, int out_size, void* d_ws, size_t ws_size,
                              hipStream_t stream){
    int map[18]; for(int i=0;i<18;i++) map[i]=i;
    if(n_in>=18 && in_sizes[0]==6400000){
        const int a[18] = {14,17,16,13,15,0,2,1,4,3,6,5,8,7,10,9,12,11};
        for(int i=0;i<18;i++) map[i]=a[i];
    }
    const void* prop = d_in[map[0]];
    const void* val  = d_in[map[1]];
    const void* same = d_in[map[2]];
    const void* pad  = d_in[map[3]];
    const void* rule = d_in[map[4]];
    const void* ent  = d_in[map[5]];
    const void* fc1w = d_in[map[6]];
    const void* fc1b = d_in[map[7]];
    const void* fc2w = d_in[map[8]];
    const void* fc2b = d_in[map[9]];
    const void* fc3w = d_in[map[10]];
    const void* fc3b = d_in[map[11]];
    const void* fc4w = d_in[map[12]];
    const void* fc4b = d_in[map[13]];
    const void* fc5w = d_in[map[14]];
    const void* fc5b = d_in[map[15]];
    const void* fc6w = d_in[map[16]];
    const void* fc6b = d_in[map[17]];

    k_detect<<<1, 256, 0, stream>>>((const u16*)ent, (const unsigned*)prop);
    k_norm<<<928, 256, 0, stream>>>(ent, rule, prop, val);
    k_mm<<<5824, 128, 0, stream>>>(fc1w, fc2w, fc3w, fc1b, fc2b, fc3b);
    k_prep<<<65, 256, 0, stream>>>(fc6w);
    k_gate<<<NI+PN, 256, 0, stream>>>(fc4w, fc4b, fc5w, fc5b);
    k_pired<<<RN, 256, 0, stream>>>();
    k_main<<<NI, 256, 0, stream>>>(fc6b, same, pad);
    k_fin<<<33, 256, 0, stream>>>((float*)d_out);
}

// Round 12
// 220.351 us; speedup vs baseline: 12.9488x; 1.0309x over previous
//
#include <hip/hip_runtime.h>
#include <hip/hip_bf16.h>

#define BATCH 32
#define MAXPV 50
#define RN 256
#define PN 256
#define DIM 128
#define NPV (BATCH*MAXPV*DIM)
#define NI (BATCH*MAXPV)   // 1600 (b,pv) pairs

typedef unsigned short u16;
typedef __attribute__((ext_vector_type(8))) short short8;
typedef __attribute__((ext_vector_type(4))) float f32x4;

// ---- all intermediates in the code object ----
__device__ float g_p[NPV], g_v[NPV], g_pa[NPV], g_pb[NPV], g_pc[NPV];
__device__ float g_ra[RN*DIM], g_rb[RN*DIM], g_rc[RN*DIM], g_pp1[PN*DIM];
__device__ float g_prop[PN*DIM], g_re[RN*DIM];
__device__ float g_raT[DIM*RN], g_rbT[DIM*RN];       // transposed [k][r]
__device__ float2 g_s1p[NI*RN];                      // (s1 signed by gate, p)
__device__ float g_piv[PN*RN];                       // pi signed by gate
__device__ float g_rmask[RN], g_regp[RN];
__device__ float g_scores[(size_t)NI*RN];            // per-(i,r) gated score (same&&pad only)
__device__ short8 g_bfrag[8][4][64];                 // fc6 B-frags [nt][ks][lane]
__device__ float g_rcA[16*4*64*8];                   // rc in MFMA-A layout [mt][ks][lane][8]
__device__ int   g_ftype, g_i64;

__device__ __forceinline__ float bf2f(u16 u){ return __uint_as_float(((unsigned)u)<<16); }
__device__ __forceinline__ float LD(const void* p, size_t i){
    return g_ftype ? bf2f(((const u16*)p)[i]) : ((const float*)p)[i];
}
__device__ __forceinline__ int LDI(const void* p, size_t i){
    return g_i64 ? (int)((const long long*)p)[i] : ((const int*)p)[i];
}
__device__ __forceinline__ short f2bf(float f){
    unsigned u = __float_as_uint(f);
    u = (u + 0x7FFFu + ((u>>16)&1u)) >> 16;
    return (short)u;
}
__device__ __forceinline__ float wred(float v){
#pragma unroll
    for(int o=32;o;o>>=1) v += __shfl_xor(v,o,64);
    return v;
}
__device__ __forceinline__ double wredd(double v){
#pragma unroll
    for(int o=32;o;o>>=1) v += __shfl_xor(v,o,64);
    return v;
}
__device__ __forceinline__ float wmax(float v){
#pragma unroll
    for(int o=32;o;o>>=1) v = fmaxf(v,__shfl_xor(v,o,64));
    return v;
}

// ---------------- K0: dtype detect ----------------
__global__ void k_detect(const u16* __restrict__ ent, const unsigned* __restrict__ prop){
    __shared__ int c[2];
    int t = threadIdx.x;
    if(t<2) c[t]=0;
    __syncthreads();
    int ee = (ent[2*(size_t)t*977]>>7)&0xFF;
    if(ee>=120 && ee<=133) atomicAdd(&c[0],1);
    if(t<32 && prop[2*t+1]==0u) atomicAdd(&c[1],1);
    __syncthreads();
    if(t==0){ g_ftype = (c[0]>=200)?1:0; g_i64 = (c[1]>=30)?1:0; }
}

// ---------------- K1: gather + l2-normalize ----------------
__global__ void k_norm(const void* __restrict__ ent, const void* __restrict__ rule,
                       const void* __restrict__ prop, const void* __restrict__ val){
    int row = blockIdx.x*4 + (threadIdx.x>>6);
    int l = threadIdx.x & 63;
    const void* src; size_t off; float* dst;
    if(row < 1600){ src=ent; off=(size_t)LDI(prop,row)*DIM; dst=g_p+(size_t)row*DIM; }
    else if(row < 3200){ int i=row-1600; src=ent; off=(size_t)LDI(val,i)*DIM; dst=g_v+(size_t)i*DIM; }
    else if(row < 3456){ int i=row-3200; src=rule; off=(size_t)i*DIM; dst=g_re+(size_t)i*DIM; }
    else { int i=row-3456; src=ent; off=(size_t)i*DIM; dst=g_prop+(size_t)i*DIM; }
    float a = LD(src,off+l), b = LD(src,off+l+64);
    float n = fmaxf(sqrtf((float)wredd((double)a*a+(double)b*b)), 1e-12f);
    dst[l]=a/n; dst[l+64]=b/n;
}

// ---------------- K2: row matmuls (fp64, 4-way ILP) ----------------
__global__ void k_mm(const void* __restrict__ fc1w, const void* __restrict__ fc2w, const void* __restrict__ fc3w,
                     const void* __restrict__ fc1b, const void* __restrict__ fc2b, const void* __restrict__ fc3b){
    __shared__ float row[DIM];
    int blk = blockIdx.x, j = threadIdx.x;
    const float* in; const void* w; size_t woff=0; float bias=0.f; float* out;
    if(blk < 1600){ in=g_p+(size_t)blk*DIM; w=fc1w; out=g_pa+(size_t)blk*DIM; }
    else if(blk < 3200){ int i=blk-1600; in=g_p+(size_t)i*DIM; w=fc2w; out=g_pb+(size_t)i*DIM; }
    else if(blk < 4800){ int i=blk-3200; in=g_p+(size_t)i*DIM; w=fc3w; out=g_pc+(size_t)i*DIM; }
    else if(blk < 5056){ int i=blk-4800; in=g_re+(size_t)i*DIM; w=fc1w; woff=DIM*DIM; out=g_ra+(size_t)i*DIM; bias=LD(fc1b,j); }
    else if(blk < 5312){ int i=blk-5056; in=g_re+(size_t)i*DIM; w=fc2w; woff=DIM*DIM; out=g_rb+(size_t)i*DIM; bias=LD(fc2b,j); }
    else if(blk < 5568){ int i=blk-5312; in=g_re+(size_t)i*DIM; w=fc3w; woff=DIM*DIM; out=g_rc+(size_t)i*DIM; bias=LD(fc3b,j); }
    else { int i=blk-5568; in=g_prop+(size_t)i*DIM; w=fc1w; out=g_pp1+(size_t)i*DIM; }
    row[j]=in[j];
    __syncthreads();
    double a0=0.0, a1=0.0, a2=0.0, a3=0.0;
    for(int k=0;k<DIM;k+=4){
        a0 += (double)row[k  ]*(double)LD(w, woff+(size_t)(k  )*DIM+j);
        a1 += (double)row[k+1]*(double)LD(w, woff+(size_t)(k+1)*DIM+j);
        a2 += (double)row[k+2]*(double)LD(w, woff+(size_t)(k+2)*DIM+j);
        a3 += (double)row[k+3]*(double)LD(w, woff+(size_t)(k+3)*DIM+j);
    }
    out[j]=(float)((double)bias + ((a0+a1)+(a2+a3)));
}

// ---------------- K3: pack fc6 B-frags + rc A-layout + transpose ra/rb ----------------
__global__ void k_prep(const void* __restrict__ fc6w){
    int blk = blockIdx.x, tid = threadIdx.x;
    if(blk < 64){                                  // raT/rbT transpose
        int idx0 = blk*256 + tid;
#pragma unroll
        for(int n=0;n<4;n++){
            int idx = idx0 + n*16384;
            int which = idx>>15;
            int k = (idx>>8)&127, r = idx&255;
            if(which) g_rbT[k*256+r] = g_rb[(size_t)r*DIM+k];
            else      g_raT[k*256+r] = g_ra[(size_t)r*DIM+k];
        }
    } else if(blk < 72){                           // bfrag nt = blk-64
        int nt = blk-64;
        int ks = tid>>6, lane = tid&63;
        int n = nt*16 + (lane&15);
        int k0 = ks*32 + (lane>>4)*8;
        short8 v;
#pragma unroll
        for(int j=0;j<8;j++) v[j] = f2bf(LD(fc6w,(size_t)(k0+j)*DIM + n));
        g_bfrag[nt][ks][lane] = v;
    } else {                                       // rcA, 2 m-tiles per block
        for(int idx=tid; idx<4096; idx+=256){
            int mt = (blk-72)*2 + (idx>>11);
            int rem = idx & 2047;
            int ks = rem>>9;
            int lane = (rem>>3)&63;
            int j = rem&7;
            int am = lane&15, quad = lane>>4;
            g_rcA[((mt*4+ks)*64+lane)*8 + j] =
                g_rc[(size_t)(mt*16+am)*DIM + ks*32 + quad*8 + j];
        }
    }
}

// ---------------- K4: gates (r-parallel, fp64 dot sign, 2-way ILP) ----------------
__global__ __launch_bounds__(256) void k_gate(
    const void* __restrict__ fc4w, const void* __restrict__ fc4b,
    const void* __restrict__ fc5w, const void* __restrict__ fc5b){
    __shared__ float s_a[DIM], s_b[DIM], s_f5[DIM];
    __shared__ double s_f4[DIM];
    const int blk = blockIdx.x, tid = threadIdx.x;
    const bool typeA = blk < NI;
    const float* arow = typeA ? g_pa + (size_t)blk*DIM : g_pp1 + (size_t)(blk-NI)*DIM;
    if(tid<DIM){ s_a[tid]=arow[tid]; s_f4[tid]=(double)LD(fc4w,tid); }
    else { int t=tid-DIM; if(typeA) s_b[t]=g_pb[(size_t)blk*DIM+t]; s_f5[t]=LD(fc5w,t); }
    __syncthreads();
    const int r = tid;
    double d0=0.0, d1=0.0; float p0=0.f, p1=0.f;
    if(typeA){
        for(int k=0;k<DIM;k+=2){
            float a1 = fmaxf(s_a[k]   + g_raT[k*256+r],     0.f);
            float a2 = fmaxf(s_a[k+1] + g_raT[(k+1)*256+r], 0.f);
            d0 += (double)a1 * s_f4[k];
            d1 += (double)a2 * s_f4[k+1];
            float b1 = fmaxf(s_b[k]   + g_rbT[k*256+r],     0.f);
            float b2 = fmaxf(s_b[k+1] + g_rbT[(k+1)*256+r], 0.f);
            p0 = fmaf(b1, s_f5[k],   p0);
            p1 = fmaf(b2, s_f5[k+1], p1);
        }
    } else {
        for(int k=0;k<DIM;k+=2){
            float a1 = fmaxf(s_a[k]   + g_raT[k*256+r],     0.f);
            float a2 = fmaxf(s_a[k+1] + g_raT[(k+1)*256+r], 0.f);
            d0 += (double)a1 * s_f4[k];
            d1 += (double)a2 * s_f4[k+1];
        }
    }
    double sd = (d0+d1) + (double)LD(fc4b,0);
    bool gate = sd > 0.0;
    float s1v = 1.f/(1.f+expf(-(float)sd));
    if(typeA){
        float p = 1.f/(1.f+expf(-((p0+p1) + LD(fc5b,0))));
        float2 o; o.x = gate ? s1v : -s1v; o.y = p;
        g_s1p[(size_t)blk*RN + r] = o;
    } else {
        g_piv[(size_t)(blk-NI)*RN + r] = gate ? s1v : -s1v;
    }
}

// ---------------- K5: reduce pi -> rule_mask + reg ----------------
__global__ void k_pired(){
    const int r = blockIdx.x, tid = threadIdx.x;
    float v = g_piv[(size_t)tid*RN + r];
    float piv = fabsf(v);
    float m = (v > 0.f) ? piv : 0.f;
    float eff = (tid==r) ? piv : (1.f - piv);
    float wgt = (tid==r) ? (float)RN : 1.f;
    float rg = -logf(eff + 1e-8f)*wgt;
    int w = tid>>6, l = tid&63;
    m = wred(m); rg = wred(rg);
    __shared__ float sm[4], sg[4];
    if(l==0){ sm[w]=m; sg[w]=rg; }
    __syncthreads();
    if(tid==0){
        g_rmask[r] = 1.f + sm[0]+sm[1]+sm[2]+sm[3];
        g_regp[r]  = sg[0]+sg[1]+sg[2]+sg[3];
    }
}

// ---------------- K6: main MFMA scoring v4 ----------------
// Only i with same&&pad. A-frags from g_rcA (coalesced), B-frags in regs,
// 2 barriers total, scores -> g_scores.
__global__ __launch_bounds__(256) void k_main(
    const void* __restrict__ fc6b,
    const void* __restrict__ same, const void* __restrict__ pad){
    const int i = blockIdx.x;
    if(LDI(same,i)!=1 || LDI(pad,i)!=1) return;   // 75% of blocks exit here
    __shared__ float s_pc[DIM];
    __shared__ float s_st[RN][4][2];              // 8 KB
    const int tid = threadIdx.x, w = tid>>6, l = tid&63;
    const int am = l&15, quad = l>>4;

    if(tid < DIM) s_pc[tid] = g_pc[(size_t)i*DIM + tid];

    short8 bA[4], bB[4];
#pragma unroll
    for(int ks=0; ks<4; ks++){ bA[ks]=g_bfrag[2*w][ks][l]; bB[ks]=g_bfrag[2*w+1][ks][l]; }
    const int n0 = w*32 + am, n1 = n0 + 16;
    const float v0 = g_v[(size_t)i*DIM + n0], v1 = g_v[(size_t)i*DIM + n1];
    const float b60 = LD(fc6b, n0), b61 = LD(fc6b, n1);

    float vl = g_v[(size_t)i*DIM + l], vh = g_v[(size_t)i*DIM + l + 64];
    const float nvb = sqrtf(wred(vl*vl + vh*vh));
    __syncthreads();                               // s_pc ready

    for(int mt=0; mt<16; mt++){
        short8 a[4];
#pragma unroll
        for(int ks=0; ks<4; ks++){
            const float* rp = &g_rcA[((mt*4+ks)*64 + l)*8];
            const float4 c0 = *(const float4*)rp;
            const float4 c1 = *(const float4*)(rp+4);
            const float4 p0 = *(const float4*)&s_pc[ks*32 + quad*8];
            const float4 p1 = *(const float4*)&s_pc[ks*32 + quad*8 + 4];
            short8 t;
            t[0]=f2bf(fmaxf(p0.x+c0.x,0.f)); t[1]=f2bf(fmaxf(p0.y+c0.y,0.f));
            t[2]=f2bf(fmaxf(p0.z+c0.z,0.f)); t[3]=f2bf(fmaxf(p0.w+c0.w,0.f));
            t[4]=f2bf(fmaxf(p1.x+c1.x,0.f)); t[5]=f2bf(fmaxf(p1.y+c1.y,0.f));
            t[6]=f2bf(fmaxf(p1.z+c1.z,0.f)); t[7]=f2bf(fmaxf(p1.w+c1.w,0.f));
            a[ks]=t;
        }
        f32x4 acc0 = {0.f,0.f,0.f,0.f}, acc1 = {0.f,0.f,0.f,0.f};
#pragma unroll
        for(int ks=0; ks<4; ks++){
            acc0 = __builtin_amdgcn_mfma_f32_16x16x32_bf16(a[ks], bA[ks], acc0, 0,0,0);
            acc1 = __builtin_amdgcn_mfma_f32_16x16x32_bf16(a[ks], bB[ks], acc1, 0,0,0);
        }
#pragma unroll
        for(int q=0; q<4; q++){
            float x0 = acc0[q] + b60;
            float x1 = acc1[q] + b61;
            float ss = x0*x0 + x1*x1;
            float dv = x0*v0 + x1*v1;
#pragma unroll
            for(int o=1;o<16;o<<=1){ ss += __shfl_xor(ss,o,64); dv += __shfl_xor(dv,o,64); }
            if(am==0){
                int row = mt*16 + quad*4 + q;
                s_st[row][w][0] = ss;
                s_st[row][w][1] = dv;
            }
        }
    }
    __syncthreads();
    {   // finalize all 256 rows (same==1, pad==1 guaranteed)
        const int r = tid;
        float ss = s_st[r][0][0]+s_st[r][1][0]+s_st[r][2][0]+s_st[r][3][0];
        float dv = s_st[r][0][1]+s_st[r][1][1]+s_st[r][2][1]+s_st[r][3][1];
        float2 sp = g_s1p[(size_t)i*RN + r];
        float s1 = fabsf(sp.x);
        float gate = (sp.x > 0.f) ? 1.f : 0.f;
        float pp = sp.y;
        float nx = sqrtf(ss);
        float clipnx = fmaxf(nx, 1e-12f);
        float gvn = nx/clipnx;
        float denom = fmaxf(nvb*gvn, 1e-8f);
        float cosv = (dv/clipnx)/denom;
        float s2 = 0.5f*cosv + 0.5f;
        float sc = s1*(pp + (1.f-pp)*s2);
        g_scores[(size_t)i*RN + r] = sc * gate;
    }
}

// ---------------- K7: pooled max (per-b) + cheap-path scores + reg mean ----------------
__global__ void k_fin(float* __restrict__ out,
                      const void* __restrict__ same, const void* __restrict__ pad){
    const int blk = blockIdx.x, tid = threadIdx.x;
    const int w = tid>>6, l = tid&63;
    __shared__ float s[4];
    if(blk < 32){
        __shared__ int s_same[MAXPV], s_pad[MAXPV];
        if(tid < MAXPV){
            s_same[tid] = LDI(same, (size_t)blk*MAXPV + tid);
            s_pad[tid]  = LDI(pad,  (size_t)blk*MAXPV + tid);
        }
        __syncthreads();
        float ssum = 0.f;
        for(int pv=0; pv<MAXPV; pv++){
            if(!s_pad[pv]) continue;                       // block-uniform
            const size_t i = (size_t)blk*MAXPV + pv;
            if(s_same[pv]==1) ssum += g_scores[i*RN + tid];
            else { float sx = g_s1p[i*RN + tid].x; ssum += (sx > 0.f) ? (1.f - sx) : 0.f; }
        }
        float sc = ssum / g_rmask[tid];
        float m = wmax(sc);
        if(l==0) s[w]=m;
        __syncthreads();
        if(tid==0) out[blk] = fmaxf(fmaxf(s[0],s[1]), fmaxf(s[2],s[3]));
    } else {
        float v = g_regp[tid];
        v = wred(v);
        if(l==0) s[w]=v;
        __syncthreads();
        if(tid==0) out[32] = (s[0]+s[1]+s[2]+s[3]) / (float)(RN*PN);
    }
}

extern "C" void kernel_launch(void* const* d_in, const int* in_sizes, int n_in,
                              void* d_out, int out_size, void* d_ws, size_t ws_size,
                              hipStream_t stream){
    int map[18]; for(int i=0;i<18;i++) map[i]=i;
    if(n_in>=18 && in_sizes[0]==6400000){
        const int a[18] = {14,17,16,13,15,0,2,1,4,3,6,5,8,7,10,9,12,11};
        for(int i=0;i<18;i++) map[i]=a[i];
    }
    const void* prop = d_in[map[0]];
    const void* val  = d_in[map[1]];
    const void* same = d_in[map[2]];
    const void* pad  = d_in[map[3]];
    const void* rule = d_in[map[4]];
    const void* ent  = d_in[map[5]];
    const void* fc1w = d_in[map[6]];
    const void* fc1b = d_in[map[7]];
    const void* fc2w = d_in[map[8]];
    const void* fc2b = d_in[map[9]];
    const void* fc3w = d_in[map[10]];
    const void* fc3b = d_in[map[11]];
    const void* fc4w = d_in[map[12]];
    const void* fc4b = d_in[map[13]];
    const void* fc5w = d_in[map[14]];
    const void* fc5b = d_in[map[15]];
    const void* fc6w = d_in[map[16]];
    const void* fc6b = d_in[map[17]];

    k_detect<<<1, 256, 0, stream>>>((const u16*)ent, (const unsigned*)prop);
    k_norm<<<928, 256, 0, stream>>>(ent, rule, prop, val);
    k_mm<<<5824, 128, 0, stream>>>(fc1w, fc2w, fc3w, fc1b, fc2b, fc3b);
    k_prep<<<80, 256, 0, stream>>>(fc6w);
    k_gate<<<NI+PN, 256, 0, stream>>>(fc4w, fc4b, fc5w, fc5b);
    k_pired<<<RN, 256, 0, stream>>>();
    k_main<<<NI, 256, 0, stream>>>(fc6b, same, pad);
    k_fin<<<33, 256, 0, stream>>>((float*)d_out, same, pad);
}

// Round 13
// 217.562 us; speedup vs baseline: 13.1149x; 1.0128x over previous
//
#include <hip/hip_runtime.h>
#include <hip/hip_bf16.h>

#define BATCH 32
#define MAXPV 50
#define RN 256
#define PN 256
#define DIM 128
#define NPV (BATCH*MAXPV*DIM)
#define NI (BATCH*MAXPV)   // 1600 (b,pv) pairs

typedef unsigned short u16;
typedef __attribute__((ext_vector_type(8))) short short8;
typedef __attribute__((ext_vector_type(4))) float f32x4;

// ---- all intermediates in the code object ----
__device__ float g_p[NPV], g_v[NPV], g_pa[NPV], g_pb[NPV], g_pc[NPV];
__device__ float g_ra[RN*DIM], g_rb[RN*DIM], g_rc[RN*DIM], g_pp1[PN*DIM];
__device__ float g_prop[PN*DIM], g_re[RN*DIM];
__device__ float g_raT[DIM*RN], g_rbT[DIM*RN];       // transposed [k][r]
__device__ float2 g_s1p[NI*RN];                      // (s1 signed by gate, p)
__device__ float g_piv[PN*RN];                       // pi signed by gate
__device__ float g_rmask[RN], g_regp[RN];
__device__ float g_scores[(size_t)NI*RN];            // per-(i,r) gated score (same&&pad only)
__device__ short8 g_bfrag[8][4][64];                 // fc6 B-frags [nt][ks][lane]
__device__ float g_rcA[16*4*64*8];                   // rc in MFMA-A layout [mt][ks][lane][8]
__device__ int   g_ftype, g_i64;

__device__ __forceinline__ float bf2f(u16 u){ return __uint_as_float(((unsigned)u)<<16); }
__device__ __forceinline__ float LD(const void* p, size_t i){
    return g_ftype ? bf2f(((const u16*)p)[i]) : ((const float*)p)[i];
}
__device__ __forceinline__ int LDI(const void* p, size_t i){
    return g_i64 ? (int)((const long long*)p)[i] : ((const int*)p)[i];
}
__device__ __forceinline__ short f2bf(float f){
    unsigned u = __float_as_uint(f);
    u = (u + 0x7FFFu + ((u>>16)&1u)) >> 16;
    return (short)u;
}
__device__ __forceinline__ float wred(float v){
#pragma unroll
    for(int o=32;o;o>>=1) v += __shfl_xor(v,o,64);
    return v;
}
__device__ __forceinline__ double wredd(double v){
#pragma unroll
    for(int o=32;o;o>>=1) v += __shfl_xor(v,o,64);
    return v;
}
__device__ __forceinline__ float wmax(float v){
#pragma unroll
    for(int o=32;o;o>>=1) v = fmaxf(v,__shfl_xor(v,o,64));
    return v;
}

// ---------------- K0: dtype detect ----------------
__global__ void k_detect(const u16* __restrict__ ent, const unsigned* __restrict__ prop){
    __shared__ int c[2];
    int t = threadIdx.x;
    if(t<2) c[t]=0;
    __syncthreads();
    int ee = (ent[2*(size_t)t*977]>>7)&0xFF;
    if(ee>=120 && ee<=133) atomicAdd(&c[0],1);
    if(t<32 && prop[2*t+1]==0u) atomicAdd(&c[1],1);
    __syncthreads();
    if(t==0){ g_ftype = (c[0]>=200)?1:0; g_i64 = (c[1]>=30)?1:0; }
}

// ---------------- K1: gather + l2-normalize ----------------
__global__ void k_norm(const void* __restrict__ ent, const void* __restrict__ rule,
                       const void* __restrict__ prop, const void* __restrict__ val){
    int row = blockIdx.x*4 + (threadIdx.x>>6);
    int l = threadIdx.x & 63;
    const void* src; size_t off; float* dst;
    if(row < 1600){ src=ent; off=(size_t)LDI(prop,row)*DIM; dst=g_p+(size_t)row*DIM; }
    else if(row < 3200){ int i=row-1600; src=ent; off=(size_t)LDI(val,i)*DIM; dst=g_v+(size_t)i*DIM; }
    else if(row < 3456){ int i=row-3200; src=rule; off=(size_t)i*DIM; dst=g_re+(size_t)i*DIM; }
    else { int i=row-3456; src=ent; off=(size_t)i*DIM; dst=g_prop+(size_t)i*DIM; }
    float a = LD(src,off+l), b = LD(src,off+l+64);
    float n = fmaxf(sqrtf((float)wredd((double)a*a+(double)b*b)), 1e-12f);
    dst[l]=a/n; dst[l+64]=b/n;
}

// ---------------- K2: row matmuls v2 — 16 rows/block, w staged in LDS ----------------
// tiles: [0,100) pa | [100,200) pb | [200,300) pc | [300,316) ra | [316,332) rb
//        [332,348) rc | [348,364) pp1
__global__ __launch_bounds__(256) void k_mm(
    const void* __restrict__ fc1w, const void* __restrict__ fc2w, const void* __restrict__ fc3w,
    const void* __restrict__ fc1b, const void* __restrict__ fc2b, const void* __restrict__ fc3b){
    __shared__ float s_w[64*DIM];       // 32 KB (k-half of weights, fp32)
    __shared__ float s_in[16*DIM];      // 8 KB
    __shared__ float s_bias[DIM];
    const int blk = blockIdx.x, tid = threadIdx.x;
    const float* in; const void* w; size_t woff=0; const void* bptr=nullptr; float* out; int row0;
    if(blk < 100){ row0=blk*16; in=g_p; w=fc1w; out=g_pa; }
    else if(blk < 200){ row0=(blk-100)*16; in=g_p; w=fc2w; out=g_pb; }
    else if(blk < 300){ row0=(blk-200)*16; in=g_p; w=fc3w; out=g_pc; }
    else if(blk < 316){ row0=(blk-300)*16; in=g_re; w=fc1w; woff=DIM*DIM; bptr=fc1b; out=g_ra; }
    else if(blk < 332){ row0=(blk-316)*16; in=g_re; w=fc2w; woff=DIM*DIM; bptr=fc2b; out=g_rb; }
    else if(blk < 348){ row0=(blk-332)*16; in=g_re; w=fc3w; woff=DIM*DIM; bptr=fc3b; out=g_rc; }
    else { row0=(blk-348)*16; in=g_prop; w=fc1w; out=g_pp1; }
    for(int t=tid; t<16*DIM; t+=256) s_in[t] = in[(size_t)row0*DIM + t];
    if(tid<DIM) s_bias[tid] = bptr ? LD(bptr,tid) : 0.f;
    const int j = tid & 127;
    const int rb8 = (tid>>7)*8;
    double acc[8] = {0,0,0,0,0,0,0,0};
    for(int half=0; half<2; half++){
        __syncthreads();
        for(int t=tid; t<64*DIM; t+=256)
            s_w[t] = LD(w, woff + (size_t)(half*64 + (t>>7))*DIM + (t&127));
        __syncthreads();
        for(int k=0;k<64;k++){
            float wk = s_w[k*DIM + j];
#pragma unroll
            for(int rr=0;rr<8;rr++)
                acc[rr] += (double)s_in[(rb8+rr)*DIM + half*64 + k]*(double)wk;
        }
    }
    const double bj = (double)s_bias[j];
#pragma unroll
    for(int rr=0;rr<8;rr++) out[(size_t)(row0+rb8+rr)*DIM + j] = (float)(bj + acc[rr]);
}

// ---------------- K3: pack fc6 B-frags + rc A-layout + transpose ra/rb ----------------
__global__ void k_prep(const void* __restrict__ fc6w){
    int blk = blockIdx.x, tid = threadIdx.x;
    if(blk < 64){                                  // raT/rbT transpose
        int idx0 = blk*256 + tid;
#pragma unroll
        for(int n=0;n<4;n++){
            int idx = idx0 + n*16384;
            int which = idx>>15;
            int k = (idx>>8)&127, r = idx&255;
            if(which) g_rbT[k*256+r] = g_rb[(size_t)r*DIM+k];
            else      g_raT[k*256+r] = g_ra[(size_t)r*DIM+k];
        }
    } else if(blk < 72){                           // bfrag nt = blk-64
        int nt = blk-64;
        int ks = tid>>6, lane = tid&63;
        int n = nt*16 + (lane&15);
        int k0 = ks*32 + (lane>>4)*8;
        short8 v;
#pragma unroll
        for(int j=0;j<8;j++) v[j] = f2bf(LD(fc6w,(size_t)(k0+j)*DIM + n));
        g_bfrag[nt][ks][lane] = v;
    } else {                                       // rcA, 2 m-tiles per block
        for(int idx=tid; idx<4096; idx+=256){
            int mt = (blk-72)*2 + (idx>>11);
            int rem = idx & 2047;
            int ks = rem>>9;
            int lane = (rem>>3)&63;
            int j = rem&7;
            int am = lane&15, quad = lane>>4;
            g_rcA[((mt*4+ks)*64+lane)*8 + j] =
                g_rc[(size_t)(mt*16+am)*DIM + ks*32 + quad*8 + j];
        }
    }
}

// ---------------- K4: gates v2 — 4 rows per block ----------------
// blocks [0,400): (b,pv) rows -> s1,p ; [400,464): prop rows -> pi
__global__ __launch_bounds__(256) void k_gate(
    const void* __restrict__ fc4w, const void* __restrict__ fc4b,
    const void* __restrict__ fc5w, const void* __restrict__ fc5b){
    __shared__ float s_a[4][DIM], s_b[4][DIM], s_f5[DIM];
    __shared__ double s_f4[DIM];
    const int blk = blockIdx.x, tid = threadIdx.x;
    const bool typeA = blk < 400;
    const int i0 = typeA ? blk*4 : (blk-400)*4;
    if(tid<DIM){ s_f4[tid]=(double)LD(fc4w,tid); s_f5[tid]=LD(fc5w,tid); }
    for(int t=tid; t<4*DIM; t+=256){
        int ii=t>>7, k=t&127;
        s_a[ii][k] = typeA ? g_pa[(size_t)(i0+ii)*DIM+k] : g_pp1[(size_t)(i0+ii)*DIM+k];
        if(typeA) s_b[ii][k] = g_pb[(size_t)(i0+ii)*DIM+k];
    }
    __syncthreads();
    const int r = tid;
    double d[4]={0.0,0.0,0.0,0.0}; float pq[4]={0.f,0.f,0.f,0.f};
    if(typeA){
        for(int k=0;k<DIM;k++){
            float rav = g_raT[k*256+r];
            float rbv = g_rbT[k*256+r];
            double f4k = s_f4[k]; float f5k = s_f5[k];
#pragma unroll
            for(int ii=0;ii<4;ii++){
                d[ii] += (double)fmaxf(s_a[ii][k]+rav,0.f)*f4k;
                pq[ii] = fmaf(fmaxf(s_b[ii][k]+rbv,0.f), f5k, pq[ii]);
            }
        }
    } else {
        for(int k=0;k<DIM;k++){
            float rav = g_raT[k*256+r];
            double f4k = s_f4[k];
#pragma unroll
            for(int ii=0;ii<4;ii++)
                d[ii] += (double)fmaxf(s_a[ii][k]+rav,0.f)*f4k;
        }
    }
    const double b4 = (double)LD(fc4b,0);
    const float b5 = LD(fc5b,0);
#pragma unroll
    for(int ii=0;ii<4;ii++){
        double sd = d[ii] + b4;
        bool gate = sd > 0.0;
        float s1v = 1.f/(1.f+expf(-(float)sd));
        if(typeA){
            float p = 1.f/(1.f+expf(-(pq[ii] + b5)));
            float2 o; o.x = gate ? s1v : -s1v; o.y = p;
            g_s1p[(size_t)(i0+ii)*RN + r] = o;
        } else {
            g_piv[(size_t)(i0+ii)*RN + r] = gate ? s1v : -s1v;
        }
    }
}

// ---------------- K5: reduce pi -> rule_mask + reg ----------------
__global__ void k_pired(){
    const int r = blockIdx.x, tid = threadIdx.x;
    float v = g_piv[(size_t)tid*RN + r];
    float piv = fabsf(v);
    float m = (v > 0.f) ? piv : 0.f;
    float eff = (tid==r) ? piv : (1.f - piv);
    float wgt = (tid==r) ? (float)RN : 1.f;
    float rg = -logf(eff + 1e-8f)*wgt;
    int w = tid>>6, l = tid&63;
    m = wred(m); rg = wred(rg);
    __shared__ float sm[4], sg[4];
    if(l==0){ sm[w]=m; sg[w]=rg; }
    __syncthreads();
    if(tid==0){
        g_rmask[r] = 1.f + sm[0]+sm[1]+sm[2]+sm[3];
        g_regp[r]  = sg[0]+sg[1]+sg[2]+sg[3];
    }
}

// ---------------- K6: main MFMA scoring v5 — M-split + rcA prefetch ----------------
// block = i*2 + h; h selects rules [h*128, h*128+128). Only same&&pad i compute.
__global__ __launch_bounds__(256) void k_main(
    const void* __restrict__ fc6b,
    const void* __restrict__ same, const void* __restrict__ pad){
    const int blk = blockIdx.x;            // 3200
    const int i = blk >> 1, h = blk & 1;
    if(LDI(same,i)!=1 || LDI(pad,i)!=1) return;
    __shared__ float s_pc[DIM];
    __shared__ float s_st[128][4][2];      // 4 KB
    const int tid = threadIdx.x, w = tid>>6, l = tid&63;
    const int am = l&15, quad = l>>4;

    if(tid < DIM) s_pc[tid] = g_pc[(size_t)i*DIM + tid];

    short8 bA[4], bB[4];
#pragma unroll
    for(int ks=0; ks<4; ks++){ bA[ks]=g_bfrag[2*w][ks][l]; bB[ks]=g_bfrag[2*w+1][ks][l]; }
    const int n0 = w*32 + am, n1 = n0 + 16;
    const float v0 = g_v[(size_t)i*DIM + n0], v1 = g_v[(size_t)i*DIM + n1];
    const float b60 = LD(fc6b, n0), b61 = LD(fc6b, n1);

    float vl = g_v[(size_t)i*DIM + l], vh = g_v[(size_t)i*DIM + l + 64];
    const float nvb = sqrtf(wred(vl*vl + vh*vh));
    __syncthreads();                       // s_pc ready

    int mt = h*8;
    float4 c[8];                           // current rcA [ks*2+half]
#pragma unroll
    for(int ks=0; ks<4; ks++){
        const float* rp = &g_rcA[((mt*4+ks)*64 + l)*8];
        c[2*ks]   = *(const float4*)rp;
        c[2*ks+1] = *(const float4*)(rp+4);
    }
    for(int mtl=0; mtl<8; mtl++){
        float4 n[8];
        if(mtl < 7){                       // prefetch next mt
#pragma unroll
            for(int ks=0; ks<4; ks++){
                const float* rp = &g_rcA[(((mt+1)*4+ks)*64 + l)*8];
                n[2*ks]   = *(const float4*)rp;
                n[2*ks+1] = *(const float4*)(rp+4);
            }
        }
        short8 a[4];
#pragma unroll
        for(int ks=0; ks<4; ks++){
            const float4 p0 = *(const float4*)&s_pc[ks*32 + quad*8];
            const float4 p1 = *(const float4*)&s_pc[ks*32 + quad*8 + 4];
            const float4 c0 = c[2*ks], c1 = c[2*ks+1];
            short8 t;
            t[0]=f2bf(fmaxf(p0.x+c0.x,0.f)); t[1]=f2bf(fmaxf(p0.y+c0.y,0.f));
            t[2]=f2bf(fmaxf(p0.z+c0.z,0.f)); t[3]=f2bf(fmaxf(p0.w+c0.w,0.f));
            t[4]=f2bf(fmaxf(p1.x+c1.x,0.f)); t[5]=f2bf(fmaxf(p1.y+c1.y,0.f));
            t[6]=f2bf(fmaxf(p1.z+c1.z,0.f)); t[7]=f2bf(fmaxf(p1.w+c1.w,0.f));
            a[ks]=t;
        }
        f32x4 acc0 = {0.f,0.f,0.f,0.f}, acc1 = {0.f,0.f,0.f,0.f};
#pragma unroll
        for(int ks=0; ks<4; ks++){
            acc0 = __builtin_amdgcn_mfma_f32_16x16x32_bf16(a[ks], bA[ks], acc0, 0,0,0);
            acc1 = __builtin_amdgcn_mfma_f32_16x16x32_bf16(a[ks], bB[ks], acc1, 0,0,0);
        }
#pragma unroll
        for(int q=0; q<4; q++){
            float x0 = acc0[q] + b60;
            float x1 = acc1[q] + b61;
            float ss = x0*x0 + x1*x1;
            float dv = x0*v0 + x1*v1;
#pragma unroll
            for(int o=1;o<16;o<<=1){ ss += __shfl_xor(ss,o,64); dv += __shfl_xor(dv,o,64); }
            if(am==0){
                int row = mtl*16 + quad*4 + q;
                s_st[row][w][0] = ss;
                s_st[row][w][1] = dv;
            }
        }
#pragma unroll
        for(int x=0;x<8;x++) c[x] = n[x];
        mt++;
    }
    __syncthreads();
    if(tid < 128){
        const int r = h*128 + tid;
        float ss = s_st[tid][0][0]+s_st[tid][1][0]+s_st[tid][2][0]+s_st[tid][3][0];
        float dv = s_st[tid][0][1]+s_st[tid][1][1]+s_st[tid][2][1]+s_st[tid][3][1];
        float2 sp = g_s1p[(size_t)i*RN + r];
        float s1 = fabsf(sp.x);
        float gate = (sp.x > 0.f) ? 1.f : 0.f;
        float pp = sp.y;
        float nx = sqrtf(ss);
        float clipnx = fmaxf(nx, 1e-12f);
        float gvn = nx/clipnx;
        float denom = fmaxf(nvb*gvn, 1e-8f);
        float cosv = (dv/clipnx)/denom;
        float s2 = 0.5f*cosv + 0.5f;
        float sc = s1*(pp + (1.f-pp)*s2);
        g_scores[(size_t)i*RN + r] = sc * gate;
    }
}

// ---------------- K7: pooled max (per-b) + cheap-path scores + reg mean ----------------
__global__ void k_fin(float* __restrict__ out,
                      const void* __restrict__ same, const void* __restrict__ pad){
    const int blk = blockIdx.x, tid = threadIdx.x;
    const int w = tid>>6, l = tid&63;
    __shared__ float s[4];
    if(blk < 32){
        __shared__ int s_same[MAXPV], s_pad[MAXPV];
        if(tid < MAXPV){
            s_same[tid] = LDI(same, (size_t)blk*MAXPV + tid);
            s_pad[tid]  = LDI(pad,  (size_t)blk*MAXPV + tid);
        }
        __syncthreads();
        float ssum = 0.f;
        for(int pv=0; pv<MAXPV; pv++){
            if(!s_pad[pv]) continue;                       // block-uniform
            const size_t i = (size_t)blk*MAXPV + pv;
            if(s_same[pv]==1) ssum += g_scores[i*RN + tid];
            else { float sx = g_s1p[i*RN + tid].x; ssum += (sx > 0.f) ? (1.f - sx) : 0.f; }
        }
        float sc = ssum / g_rmask[tid];
        float m = wmax(sc);
        if(l==0) s[w]=m;
        __syncthreads();
        if(tid==0) out[blk] = fmaxf(fmaxf(s[0],s[1]), fmaxf(s[2],s[3]));
    } else {
        float v = g_regp[tid];
        v = wred(v);
        if(l==0) s[w]=v;
        __syncthreads();
        if(tid==0) out[32] = (s[0]+s[1]+s[2]+s[3]) / (float)(RN*PN);
    }
}

extern "C" void kernel_launch(void* const* d_in, const int* in_sizes, int n_in,
                              void* d_out, int out_size, void* d_ws, size_t ws_size,
                              hipStream_t stream){
    int map[18]; for(int i=0;i<18;i++) map[i]=i;
    if(n_in>=18 && in_sizes[0]==6400000){
        const int a[18] = {14,17,16,13,15,0,2,1,4,3,6,5,8,7,10,9,12,11};
        for(int i=0;i<18;i++) map[i]=a[i];
    }
    const void* prop = d_in[map[0]];
    const void* val  = d_in[map[1]];
    const void* same = d_in[map[2]];
    const void* pad  = d_in[map[3]];
    const void* rule = d_in[map[4]];
    const void* ent  = d_in[map[5]];
    const void* fc1w = d_in[map[6]];
    const void* fc1b = d_in[map[7]];
    const void* fc2w = d_in[map[8]];
    const void* fc2b = d_in[map[9]];
    const void* fc3w = d_in[map[10]];
    const void* fc3b = d_in[map[11]];
    const void* fc4w = d_in[map[12]];
    const void* fc4b = d_in[map[13]];
    const void* fc5w = d_in[map[14]];
    const void* fc5b = d_in[map[15]];
    const void* fc6w = d_in[map[16]];
    const void* fc6b = d_in[map[17]];

    k_detect<<<1, 256, 0, stream>>>((const u16*)ent, (const unsigned*)prop);
    k_norm<<<928, 256, 0, stream>>>(ent, rule, prop, val);
    k_mm<<<364, 256, 0, stream>>>(fc1w, fc2w, fc3w, fc1b, fc2b, fc3b);
    k_prep<<<80, 256, 0, stream>>>(fc6w);
    k_gate<<<464, 256, 0, stream>>>(fc4w, fc4b, fc5w, fc5b);
    k_pired<<<RN, 256, 0, stream>>>();
    k_main<<<NI*2, 256, 0, stream>>>(fc6b, same, pad);
    k_fin<<<33, 256, 0, stream>>>((float*)d_out, same, pad);
}

// Round 14
// 214.186 us; speedup vs baseline: 13.3215x; 1.0158x over previous
//
#include <hip/hip_runtime.h>
#include <hip/hip_bf16.h>

#define BATCH 32
#define MAXPV 50
#define RN 256
#define PN 256
#define DIM 128
#define NPV (BATCH*MAXPV*DIM)
#define NI (BATCH*MAXPV)   // 1600 (b,pv) pairs

typedef unsigned short u16;
typedef __attribute__((ext_vector_type(8))) short short8;
typedef __attribute__((ext_vector_type(4))) float f32x4;

// ---- intermediates in the code object ----
__device__ float g_p[NPV], g_v[NPV], g_pa[NPV], g_pb[NPV], g_pc[NPV];
__device__ float g_pp1[PN*DIM], g_prop[PN*DIM], g_re[RN*DIM];
__device__ float g_raT[DIM*RN], g_rbT[DIM*RN];       // transposed [k][r]
__device__ float2 g_s1p[NI*RN];                      // (s1 signed by gate, p)
__device__ float g_rmask[RN], g_regp[RN];
__device__ float g_scores[(size_t)NI*RN];            // per-(i,r) gated score (same&&pad only)
__device__ short8 g_bfrag[8][4][64];                 // fc6 B-frags [nt][ks][lane]
__device__ float g_rcA[16*4*64*8];                   // rc in MFMA-A layout [mt][ks][lane][8]

__device__ __forceinline__ float bf2f(u16 u){ return __uint_as_float(((unsigned)u)<<16); }
__device__ __forceinline__ float LD(const void* p, size_t i, bool bf){
    return bf ? bf2f(((const u16*)p)[i]) : ((const float*)p)[i];
}
__device__ __forceinline__ int LDI(const void* p, size_t i, bool w64){
    return w64 ? (int)((const long long*)p)[i] : ((const int*)p)[i];
}
__device__ __forceinline__ short f2bf(float f){
    unsigned u = __float_as_uint(f);
    u = (u + 0x7FFFu + ((u>>16)&1u)) >> 16;
    return (short)u;
}
__device__ __forceinline__ unsigned f2bf2(float x, float y){
    float2 f; f.x=x; f.y=y;
    __hip_bfloat162 h = __float22bfloat162_rn(f);      // v_cvt_pk_bf16_f32
    union { __hip_bfloat162 h; unsigned u; } c; c.h=h; return c.u;
}
// ---- per-block inline dtype detection (wave-uniform, ~6 insts) ----
__device__ __forceinline__ bool det_bf16(const void* ent){
    int l = threadIdx.x & 63;
    u16 v = ((const u16*)ent)[(size_t)2*(l*4)*977];    // max idx 492,408: safe both dtypes
    int e = (v>>7)&0xFF;
    return __popcll(__ballot(e>=120 && e<=133)) >= 48; // bf16 ~64/64, fp32 ~6/64
}
__device__ __forceinline__ bool det_i64(const void* prop){
    int l = threadIdx.x & 63;
    bool z = (l<32) ? (((const unsigned*)prop)[2*l+1]==0u) : false;
    return __popcll(__ballot(z)) >= 30;                // int64: 32/32 odd words zero
}
__device__ __forceinline__ float wred(float v){
#pragma unroll
    for(int o=32;o;o>>=1) v += __shfl_xor(v,o,64);
    return v;
}
__device__ __forceinline__ double wredd(double v){
#pragma unroll
    for(int o=32;o;o>>=1) v += __shfl_xor(v,o,64);
    return v;
}
__device__ __forceinline__ float wmax(float v){
#pragma unroll
    for(int o=32;o;o>>=1) v = fmaxf(v,__shfl_xor(v,o,64));
    return v;
}

// ---------------- K1: gather + l2-normalize (+ bfrag pack + accum init) ----------------
// blocks [0,928): 4 rows each of {p,v,re,prop}; [928,936): bfrag nt=blk-928 (+init on nt==0)
__global__ void k_norm(const void* __restrict__ ent, const void* __restrict__ rule,
                       const void* __restrict__ prop, const void* __restrict__ val,
                       const void* __restrict__ fc6w){
    const bool bf = det_bf16(ent);
    const int blk = blockIdx.x, tid = threadIdx.x;
    if(blk >= 928){
        int nt = blk-928;
        int ks = tid>>6, lane = tid&63;
        int n = nt*16 + (lane&15);
        int k0 = ks*32 + (lane>>4)*8;
        short8 v;
#pragma unroll
        for(int j=0;j<8;j++) v[j] = f2bf(LD(fc6w,(size_t)(k0+j)*DIM + n, bf));
        g_bfrag[nt][ks][lane] = v;
        if(nt==0){ g_rmask[tid] = 1.f; g_regp[tid] = 0.f; }
        return;
    }
    const bool w64 = det_i64(prop);
    int row = blk*4 + (tid>>6);
    int l = tid & 63;
    const void* src; size_t off; float* dst;
    if(row < 1600){ src=ent; off=(size_t)LDI(prop,row,w64)*DIM; dst=g_p+(size_t)row*DIM; }
    else if(row < 3200){ int i=row-1600; src=ent; off=(size_t)LDI(val,i,w64)*DIM; dst=g_v+(size_t)i*DIM; }
    else if(row < 3456){ int i=row-3200; src=rule; off=(size_t)i*DIM; dst=g_re+(size_t)i*DIM; }
    else { int i=row-3456; src=ent; off=(size_t)i*DIM; dst=g_prop+(size_t)i*DIM; }
    float a = LD(src,off+l,bf), b = LD(src,off+l+64,bf);
    float n = fmaxf(sqrtf((float)wredd((double)a*a+(double)b*b)), 1e-12f);
    dst[l]=a/n; dst[l+64]=b/n;
}

// ---------------- K2: row matmuls + direct packed outputs ----------------
// [0,100) pa | [100,200) pb | [200,300) pc | [300,316) raT | [316,332) rbT
// [332,348) rcA | [348,364) pp1
__global__ __launch_bounds__(256) void k_mm(
    const void* __restrict__ ent,
    const void* __restrict__ fc1w, const void* __restrict__ fc2w, const void* __restrict__ fc3w,
    const void* __restrict__ fc1b, const void* __restrict__ fc2b, const void* __restrict__ fc3b){
    __shared__ float s_w[64*DIM];       // 32 KB (k-half of weights, fp32)
    __shared__ float s_in[16*DIM];      // 8 KB
    __shared__ float s_bias[DIM];
    const bool bf = det_bf16(ent);
    const int blk = blockIdx.x, tid = threadIdx.x;
    const float* in; const void* w; size_t woff=0; const void* bptr=nullptr;
    float* out=nullptr; int row0; int mode=0;
    if(blk < 100){ row0=blk*16; in=g_p; w=fc1w; out=g_pa; }
    else if(blk < 200){ row0=(blk-100)*16; in=g_p; w=fc2w; out=g_pb; }
    else if(blk < 300){ row0=(blk-200)*16; in=g_p; w=fc3w; out=g_pc; }
    else if(blk < 316){ row0=(blk-300)*16; in=g_re; w=fc1w; woff=DIM*DIM; bptr=fc1b; mode=1; }
    else if(blk < 332){ row0=(blk-316)*16; in=g_re; w=fc2w; woff=DIM*DIM; bptr=fc2b; mode=2; }
    else if(blk < 348){ row0=(blk-332)*16; in=g_re; w=fc3w; woff=DIM*DIM; bptr=fc3b; mode=3; }
    else { row0=(blk-348)*16; in=g_prop; w=fc1w; out=g_pp1; }
    for(int t=tid; t<16*DIM; t+=256) s_in[t] = in[(size_t)row0*DIM + t];
    if(tid<DIM) s_bias[tid] = bptr ? LD(bptr,tid,bf) : 0.f;
    const int j = tid & 127;
    const int rb8 = (tid>>7)*8;
    double acc[8] = {0,0,0,0,0,0,0,0};
    for(int half=0; half<2; half++){
        __syncthreads();
        for(int t=tid; t<64*DIM; t+=256)
            s_w[t] = LD(w, woff + (size_t)(half*64 + (t>>7))*DIM + (t&127), bf);
        __syncthreads();
        for(int k=0;k<64;k++){
            float wk = s_w[k*DIM + j];
#pragma unroll
            for(int rr=0;rr<8;rr++)
                acc[rr] += (double)s_in[(rb8+rr)*DIM + half*64 + k]*(double)wk;
        }
    }
    const double bj = (double)s_bias[j];
#pragma unroll
    for(int rr=0;rr<8;rr++){
        const int row = row0 + rb8 + rr;
        const float vv = (float)(bj + acc[rr]);
        if(mode==0)      out[(size_t)row*DIM + j] = vv;
        else if(mode==1) g_raT[j*256 + row] = vv;
        else if(mode==2) g_rbT[j*256 + row] = vv;
        else {           // rcA scatter: row in [0,256), k=j
            int mt=row>>4, am=row&15, ks=j>>5, quad=(j>>3)&3, jj=j&7;
            g_rcA[((mt*4+ks)*64 + quad*16+am)*8 + jj] = vv;
        }
    }
}

// ---------------- K3: gates (4 rows/block) + fused pi reduction ----------------
// [0,400): (b,pv) -> s1,p ; [400,464): prop -> atomic rmask/reg
__global__ __launch_bounds__(256) void k_gate(
    const void* __restrict__ ent,
    const void* __restrict__ fc4w, const void* __restrict__ fc4b,
    const void* __restrict__ fc5w, const void* __restrict__ fc5b){
    __shared__ float s_a[4][DIM], s_b[4][DIM], s_f5[DIM];
    __shared__ double s_f4[DIM];
    const bool bf = det_bf16(ent);
    const int blk = blockIdx.x, tid = threadIdx.x;
    const bool typeA = blk < 400;
    const int i0 = typeA ? blk*4 : (blk-400)*4;
    if(tid<DIM){ s_f4[tid]=(double)LD(fc4w,tid,bf); s_f5[tid]=LD(fc5w,tid,bf); }
    for(int t=tid; t<4*DIM; t+=256){
        int ii=t>>7, k=t&127;
        s_a[ii][k] = typeA ? g_pa[(size_t)(i0+ii)*DIM+k] : g_pp1[(size_t)(i0+ii)*DIM+k];
        if(typeA) s_b[ii][k] = g_pb[(size_t)(i0+ii)*DIM+k];
    }
    __syncthreads();
    const int r = tid;
    double d[4]={0.0,0.0,0.0,0.0}; float pq[4]={0.f,0.f,0.f,0.f};
    if(typeA){
        for(int k=0;k<DIM;k++){
            float rav = g_raT[k*256+r];
            float rbv = g_rbT[k*256+r];
            double f4k = s_f4[k]; float f5k = s_f5[k];
#pragma unroll
            for(int ii=0;ii<4;ii++){
                d[ii] += (double)fmaxf(s_a[ii][k]+rav,0.f)*f4k;
                pq[ii] = fmaf(fmaxf(s_b[ii][k]+rbv,0.f), f5k, pq[ii]);
            }
        }
    } else {
        for(int k=0;k<DIM;k++){
            float rav = g_raT[k*256+r];
            double f4k = s_f4[k];
#pragma unroll
            for(int ii=0;ii<4;ii++)
                d[ii] += (double)fmaxf(s_a[ii][k]+rav,0.f)*f4k;
        }
    }
    const double b4 = (double)LD(fc4b,0,bf);
    if(typeA){
        const float b5 = LD(fc5b,0,bf);
#pragma unroll
        for(int ii=0;ii<4;ii++){
            double sd = d[ii] + b4;
            float s1v = 1.f/(1.f+expf(-(float)sd));
            float p = 1.f/(1.f+expf(-(pq[ii] + b5)));
            float2 o; o.x = (sd > 0.0) ? s1v : -s1v; o.y = p;
            g_s1p[(size_t)(i0+ii)*RN + r] = o;
        }
    } else {
        float mask_sum = 0.f, reg_sum = 0.f;
#pragma unroll
        for(int ii=0;ii<4;ii++){
            int p = i0 + ii;
            double sd = d[ii] + b4;
            float piv = 1.f/(1.f+expf(-(float)sd));
            if(sd > 0.0) mask_sum += piv;              // piv>0.5 <=> sd>0
            float eff = (p==r) ? piv : (1.f - piv);
            float wgt = (p==r) ? (float)RN : 1.f;
            reg_sum += -logf(eff + 1e-8f)*wgt;
        }
        atomicAdd(&g_rmask[r], mask_sum);
        atomicAdd(&g_regp[r], reg_sum);
    }
}

// ---------------- K4: main MFMA scoring (M-split, rcA prefetch, packed cvt) ----------------
__global__ __launch_bounds__(256) void k_main(
    const void* __restrict__ ent, const void* __restrict__ prop,
    const void* __restrict__ fc6b,
    const void* __restrict__ same, const void* __restrict__ pad){
    const int blk = blockIdx.x;            // 3200
    const int i = blk >> 1, h = blk & 1;
    const bool w64 = det_i64(prop);
    if(LDI(same,i,w64)!=1 || LDI(pad,i,w64)!=1) return;
    const bool bf = det_bf16(ent);
    __shared__ float s_pc[DIM];
    __shared__ float s_st[128][4][2];      // 4 KB
    const int tid = threadIdx.x, w = tid>>6, l = tid&63;
    const int am = l&15, quad = l>>4;

    if(tid < DIM) s_pc[tid] = g_pc[(size_t)i*DIM + tid];

    short8 bA[4], bB[4];
#pragma unroll
    for(int ks=0; ks<4; ks++){ bA[ks]=g_bfrag[2*w][ks][l]; bB[ks]=g_bfrag[2*w+1][ks][l]; }
    const int n0 = w*32 + am, n1 = n0 + 16;
    const float v0 = g_v[(size_t)i*DIM + n0], v1 = g_v[(size_t)i*DIM + n1];
    const float b60 = LD(fc6b, n0, bf), b61 = LD(fc6b, n1, bf);

    float vl = g_v[(size_t)i*DIM + l], vh = g_v[(size_t)i*DIM + l + 64];
    const float nvb = sqrtf(wred(vl*vl + vh*vh));
    __syncthreads();                       // s_pc ready

    int mt = h*8;
    float4 c[8];
#pragma unroll
    for(int ks=0; ks<4; ks++){
        const float* rp = &g_rcA[((mt*4+ks)*64 + l)*8];
        c[2*ks]   = *(const float4*)rp;
        c[2*ks+1] = *(const float4*)(rp+4);
    }
    for(int mtl=0; mtl<8; mtl++){
        float4 n[8];
        if(mtl < 7){
#pragma unroll
            for(int ks=0; ks<4; ks++){
                const float* rp = &g_rcA[(((mt+1)*4+ks)*64 + l)*8];
                n[2*ks]   = *(const float4*)rp;
                n[2*ks+1] = *(const float4*)(rp+4);
            }
        }
        short8 a[4];
#pragma unroll
        for(int ks=0; ks<4; ks++){
            const float4 p0 = *(const float4*)&s_pc[ks*32 + quad*8];
            const float4 p1 = *(const float4*)&s_pc[ks*32 + quad*8 + 4];
            const float4 c0 = c[2*ks], c1 = c[2*ks+1];
            union { short8 s; unsigned u[4]; } t;
            t.u[0] = f2bf2(fmaxf(p0.x+c0.x,0.f), fmaxf(p0.y+c0.y,0.f));
            t.u[1] = f2bf2(fmaxf(p0.z+c0.z,0.f), fmaxf(p0.w+c0.w,0.f));
            t.u[2] = f2bf2(fmaxf(p1.x+c1.x,0.f), fmaxf(p1.y+c1.y,0.f));
            t.u[3] = f2bf2(fmaxf(p1.z+c1.z,0.f), fmaxf(p1.w+c1.w,0.f));
            a[ks] = t.s;
        }
        f32x4 acc0 = {0.f,0.f,0.f,0.f}, acc1 = {0.f,0.f,0.f,0.f};
#pragma unroll
        for(int ks=0; ks<4; ks++){
            acc0 = __builtin_amdgcn_mfma_f32_16x16x32_bf16(a[ks], bA[ks], acc0, 0,0,0);
            acc1 = __builtin_amdgcn_mfma_f32_16x16x32_bf16(a[ks], bB[ks], acc1, 0,0,0);
        }
#pragma unroll
        for(int q=0; q<4; q++){
            float x0 = acc0[q] + b60;
            float x1 = acc1[q] + b61;
            float ss = x0*x0 + x1*x1;
            float dv = x0*v0 + x1*v1;
#pragma unroll
            for(int o=1;o<16;o<<=1){ ss += __shfl_xor(ss,o,64); dv += __shfl_xor(dv,o,64); }
            if(am==0){
                int row = mtl*16 + quad*4 + q;
                s_st[row][w][0] = ss;
                s_st[row][w][1] = dv;
            }
        }
#pragma unroll
        for(int x=0;x<8;x++) c[x] = n[x];
        mt++;
    }
    __syncthreads();
    if(tid < 128){
        const int r = h*128 + tid;
        float ss = s_st[tid][0][0]+s_st[tid][1][0]+s_st[tid][2][0]+s_st[tid][3][0];
        float dv = s_st[tid][0][1]+s_st[tid][1][1]+s_st[tid][2][1]+s_st[tid][3][1];
        float2 sp = g_s1p[(size_t)i*RN + r];
        float s1 = fabsf(sp.x);
        float gate = (sp.x > 0.f) ? 1.f : 0.f;
        float pp = sp.y;
        float nx = sqrtf(ss);
        float clipnx = fmaxf(nx, 1e-12f);
        float gvn = nx/clipnx;
        float denom = fmaxf(nvb*gvn, 1e-8f);
        float cosv = (dv/clipnx)/denom;
        float s2 = 0.5f*cosv + 0.5f;
        float sc = s1*(pp + (1.f-pp)*s2);
        g_scores[(size_t)i*RN + r] = sc * gate;
    }
}

// ---------------- K5: pooled max + cheap-path + reg mean ----------------
__global__ void k_fin(float* __restrict__ out, const void* __restrict__ prop,
                      const void* __restrict__ same, const void* __restrict__ pad){
    const bool w64 = det_i64(prop);
    const int blk = blockIdx.x, tid = threadIdx.x;
    const int w = tid>>6, l = tid&63;
    __shared__ float s[4];
    if(blk < 32){
        __shared__ int s_same[MAXPV], s_pad[MAXPV];
        if(tid < MAXPV){
            s_same[tid] = LDI(same, (size_t)blk*MAXPV + tid, w64);
            s_pad[tid]  = LDI(pad,  (size_t)blk*MAXPV + tid, w64);
        }
        __syncthreads();
        float ssum = 0.f;
        for(int pv=0; pv<MAXPV; pv++){
            if(!s_pad[pv]) continue;
            const size_t i = (size_t)blk*MAXPV + pv;
            if(s_same[pv]==1) ssum += g_scores[i*RN + tid];
            else { float sx = g_s1p[i*RN + tid].x; ssum += (sx > 0.f) ? (1.f - sx) : 0.f; }
        }
        float sc = ssum / g_rmask[tid];
        float m = wmax(sc);
        if(l==0) s[w]=m;
        __syncthreads();
        if(tid==0) out[blk] = fmaxf(fmaxf(s[0],s[1]), fmaxf(s[2],s[3]));
    } else {
        float v = g_regp[tid];
        v = wred(v);
        if(l==0) s[w]=v;
        __syncthreads();
        if(tid==0) out[32] = (s[0]+s[1]+s[2]+s[3]) / (float)(RN*PN);
    }
}

extern "C" void kernel_launch(void* const* d_in, const int* in_sizes, int n_in,
                              void* d_out, int out_size, void* d_ws, size_t ws_size,
                              hipStream_t stream){
    int map[18]; for(int i=0;i<18;i++) map[i]=i;
    if(n_in>=18 && in_sizes[0]==6400000){
        const int a[18] = {14,17,16,13,15,0,2,1,4,3,6,5,8,7,10,9,12,11};
        for(int i=0;i<18;i++) map[i]=a[i];
    }
    const void* prop = d_in[map[0]];
    const void* val  = d_in[map[1]];
    const void* same = d_in[map[2]];
    const void* pad  = d_in[map[3]];
    const void* rule = d_in[map[4]];
    const void* ent  = d_in[map[5]];
    const void* fc1w = d_in[map[6]];
    const void* fc1b = d_in[map[7]];
    const void* fc2w = d_in[map[8]];
    const void* fc2b = d_in[map[9]];
    const void* fc3w = d_in[map[10]];
    const void* fc3b = d_in[map[11]];
    const void* fc4w = d_in[map[12]];
    const void* fc4b = d_in[map[13]];
    const void* fc5w = d_in[map[14]];
    const void* fc5b = d_in[map[15]];
    const void* fc6w = d_in[map[16]];
    const void* fc6b = d_in[map[17]];

    k_norm<<<936, 256, 0, stream>>>(ent, rule, prop, val, fc6w);
    k_mm<<<364, 256, 0, stream>>>(ent, fc1w, fc2w, fc3w, fc1b, fc2b, fc3b);
    k_gate<<<464, 256, 0, stream>>>(ent, fc4w, fc4b, fc5w, fc5b);
    k_main<<<NI*2, 256, 0, stream>>>(ent, prop, fc6b, same, pad);
    k_fin<<<33, 256, 0, stream>>>((float*)d_out, prop, same, pad);
}